// Round 1
// baseline (898.441 us; speedup 1.0000x reference)
//
#include <hip/hip_runtime.h>
#include <math.h>

// ---------------------------------------------------------------------------
// HybridSiLUGatedAttention on MI355X (gfx950)
// B=2, S=2048, D=1024, H=16, hd=64.
// Strategy: split-bf16 (hi/lo) 3-term MFMA emulation for near-fp32 accuracy
// on all three GEMM stages; mask packed to bits; LN+gate fused into attention.
// ---------------------------------------------------------------------------

typedef __bf16 bf16x8 __attribute__((ext_vector_type(8)));
typedef __bf16 bf16x4 __attribute__((ext_vector_type(4)));
typedef float  f32x4  __attribute__((ext_vector_type(4)));

#define MFMA16(A, B, C) __builtin_amdgcn_mfma_f32_16x16x32_bf16((A), (B), (C), 0, 0, 0)

constexpr int   Bc   = 2;
constexpr int   Sc   = 2048;
constexpr int   Dc   = 1024;
constexpr int   Hc   = 16;
constexpr int   HDc  = 64;
constexpr float SCALE_C = 0.125f;   // 1/sqrt(64)
constexpr float LN_EPS_C = 1e-5f;

__device__ __forceinline__ float silu_f(float x) {
    return x / (1.0f + __expf(-x));
}

// --------------------------- elementwise fp32 -> hi/lo bf16 ----------------
__global__ __launch_bounds__(256) void convert_split_kernel(
    const float* __restrict__ X, __bf16* __restrict__ Hi, __bf16* __restrict__ Lo, int n4)
{
    int i = blockIdx.x * 256 + threadIdx.x;
    if (i >= n4) return;
    float4 v = ((const float4*)X)[i];
    float vv[4] = {v.x, v.y, v.z, v.w};
    bf16x4 h, l;
#pragma unroll
    for (int e = 0; e < 4; ++e) {
        __bf16 hh = (__bf16)vv[e];
        h[e] = hh;
        l[e] = (__bf16)(vv[e] - (float)hh);
    }
    ((bf16x4*)Hi)[i] = h;
    ((bf16x4*)Lo)[i] = l;
}

// ------------------- transpose W[K][N] -> T[N][K], split hi/lo -------------
__global__ __launch_bounds__(256) void transpose_split_kernel(
    const float* __restrict__ W, __bf16* __restrict__ Thi, __bf16* __restrict__ Tlo,
    int K, int N)
{
    __shared__ float tile[64][65];
    int kb = blockIdx.x * 64, nb = blockIdx.y * 64;
    int t = threadIdx.x;
    int i  = t >> 2;            // 0..63
    int c0 = (t & 3) * 16;      // 0,16,32,48
    const float* src = W + (size_t)(kb + i) * N + nb + c0;
#pragma unroll
    for (int e = 0; e < 4; ++e) {
        float4 v = ((const float4*)src)[e];
        tile[i][c0 + e * 4 + 0] = v.x;
        tile[i][c0 + e * 4 + 1] = v.y;
        tile[i][c0 + e * 4 + 2] = v.z;
        tile[i][c0 + e * 4 + 3] = v.w;
    }
    __syncthreads();
    int j = i;  // n-offset
#pragma unroll
    for (int e = 0; e < 4; ++e) {
        bf16x4 h, l;
#pragma unroll
        for (int u = 0; u < 4; ++u) {
            float x = tile[c0 + e * 4 + u][j];
            __bf16 hh = (__bf16)x;
            h[u] = hh;
            l[u] = (__bf16)(x - (float)hh);
        }
        size_t o = (size_t)(nb + j) * K + kb + c0 + e * 4;
        *(bf16x4*)&Thi[o] = h;
        *(bf16x4*)&Tlo[o] = l;
    }
}

// -------- mask [B,1,S,S] -> bit-pack [row][S/64] + invnorm = 1/sqrt(max(sum,1))
__global__ __launch_bounds__(256) void mask_prep_kernel(
    const int* __restrict__ mask, unsigned long long* __restrict__ bits,
    float* __restrict__ invn)
{
    int lane = threadIdx.x & 63, wid = threadIdx.x >> 6;
    int row = blockIdx.x * 4 + wid;          // 0..4095  (= b*2048+q)
    const int* mr = mask + (size_t)row * Sc;
    int cnt = 0;
    for (int t = 0; t < Sc / 64; ++t) {
        int m = mr[t * 64 + lane];
        unsigned long long w = __ballot(m != 0);
        if (lane == 0) bits[(size_t)row * (Sc / 64) + t] = w;
        cnt += (int)__popcll(w);
    }
    if (lane == 0) invn[row] = rsqrtf(fmaxf((float)cnt, 1.0f));
}

// --------------------------- split-bf16 GEMM -------------------------------
// C[M][N] = A[M][K] * B^T[N][K]   (both operands stored K-contiguous)
// EPI==0: silu epilogue, scatter to Q/K/V(t)/G.   EPI==1: plain fp32 out (N=1024).
template<int EPI>
__global__ __launch_bounds__(256) void gemm_split_kernel(
    const __bf16* __restrict__ Ah, const __bf16* __restrict__ Al,
    const __bf16* __restrict__ Bh, const __bf16* __restrict__ Bl,
    int Kdim,
    float* __restrict__ outF,
    __bf16* __restrict__ Qh, __bf16* __restrict__ Ql,
    __bf16* __restrict__ Kh, __bf16* __restrict__ Kl,
    __bf16* __restrict__ Vh, __bf16* __restrict__ Vl,
    float* __restrict__ G)
{
    constexpr int LSTR = 40;               // padded LDS row (bf16) -> 2-way max
    __shared__ __bf16 sA[2][128 * LSTR];
    __shared__ __bf16 sB[2][128 * LSTR];
    int tid = threadIdx.x, lane = tid & 63, wid = tid >> 6;
    int r = lane & 15, kg = lane >> 4;
    int wm = wid >> 1, wn = wid & 1;
    int m0 = blockIdx.x * 128, n0 = blockIdx.y * 128;
    int c1r = tid >> 2;                    // 0..63
    int ck  = (tid & 3) * 8;               // 0,8,16,24
    int c2r = c1r + 64;

    f32x4 acc[4][4] = {};

    for (int kt = 0; kt < Kdim; kt += 32) {
        // stage A/B hi+lo tiles (reg-staged vector copies)
        *(bf16x8*)&sA[0][c1r * LSTR + ck] = *(const bf16x8*)&Ah[(size_t)(m0 + c1r) * Kdim + kt + ck];
        *(bf16x8*)&sA[0][c2r * LSTR + ck] = *(const bf16x8*)&Ah[(size_t)(m0 + c2r) * Kdim + kt + ck];
        *(bf16x8*)&sA[1][c1r * LSTR + ck] = *(const bf16x8*)&Al[(size_t)(m0 + c1r) * Kdim + kt + ck];
        *(bf16x8*)&sA[1][c2r * LSTR + ck] = *(const bf16x8*)&Al[(size_t)(m0 + c2r) * Kdim + kt + ck];
        *(bf16x8*)&sB[0][c1r * LSTR + ck] = *(const bf16x8*)&Bh[(size_t)(n0 + c1r) * Kdim + kt + ck];
        *(bf16x8*)&sB[0][c2r * LSTR + ck] = *(const bf16x8*)&Bh[(size_t)(n0 + c2r) * Kdim + kt + ck];
        *(bf16x8*)&sB[1][c1r * LSTR + ck] = *(const bf16x8*)&Bl[(size_t)(n0 + c1r) * Kdim + kt + ck];
        *(bf16x8*)&sB[1][c2r * LSTR + ck] = *(const bf16x8*)&Bl[(size_t)(n0 + c2r) * Kdim + kt + ck];
        __syncthreads();

        bf16x8 afh[4], afl[4], bfh[4], bfl[4];
#pragma unroll
        for (int m = 0; m < 4; ++m) {
            int row = wm * 64 + m * 16 + r;
            afh[m] = *(bf16x8*)&sA[0][row * LSTR + kg * 8];
            afl[m] = *(bf16x8*)&sA[1][row * LSTR + kg * 8];
        }
#pragma unroll
        for (int n = 0; n < 4; ++n) {
            int col = wn * 64 + n * 16 + r;
            bfh[n] = *(bf16x8*)&sB[0][col * LSTR + kg * 8];
            bfl[n] = *(bf16x8*)&sB[1][col * LSTR + kg * 8];
        }
#pragma unroll
        for (int m = 0; m < 4; ++m)
#pragma unroll
            for (int n = 0; n < 4; ++n) {
                acc[m][n] = MFMA16(afl[m], bfh[n], acc[m][n]);
                acc[m][n] = MFMA16(afh[m], bfl[n], acc[m][n]);
                acc[m][n] = MFMA16(afh[m], bfh[n], acc[m][n]);
            }
        __syncthreads();
    }

    int sec = n0 >> 10;  // tile-uniform: 0=q 1=k 2=v 3=g (128 | 1024)
#pragma unroll
    for (int m = 0; m < 4; ++m)
#pragma unroll
        for (int n = 0; n < 4; ++n)
#pragma unroll
            for (int j = 0; j < 4; ++j) {
                int gm = m0 + wm * 64 + m * 16 + kg * 4 + j;   // token row
                int gn = n0 + wn * 64 + n * 16 + r;            // feature col
                float x = acc[m][n][j];
                if constexpr (EPI == 1) {
                    outF[(size_t)gm * 1024 + gn] = x;
                } else {
                    float p = silu_f(x);
                    if (sec == 3) {
                        G[(size_t)gm * Dc + (gn & 1023)] = p;
                    } else {
                        int f = gn & 1023, h = f >> 6, d = f & 63;
                        int b = gm >> 11, s = gm & 2047;
                        __bf16 hi = (__bf16)p;
                        __bf16 lo = (__bf16)(p - (float)hi);
                        if (sec == 0) {
                            size_t idx = ((size_t)(b * Hc + h) * Sc + s) * HDc + d;
                            Qh[idx] = hi; Ql[idx] = lo;
                        } else if (sec == 1) {
                            size_t idx = ((size_t)(b * Hc + h) * Sc + s) * HDc + d;
                            Kh[idx] = hi; Kl[idx] = lo;
                        } else {  // v stored transposed: [b,h,d,s]
                            size_t idx = ((size_t)(b * Hc + h) * HDc + d) * Sc + s;
                            Vh[idx] = hi; Vl[idx] = lo;
                        }
                    }
                }
            }
}

// --------------------------- fused attention -------------------------------
// grid: b*H*32 + h*32 + qb ; block 256 (4 waves, 16 q-rows each).
// scores = silu(q.k^T * scale) * mask * invnorm; attended = scores @ v;
// then LayerNorm over hd + gate, emitted as hi/lo bf16 in token-major layout.
__global__ __launch_bounds__(256) void attn_kernel(
    const __bf16* __restrict__ Qh, const __bf16* __restrict__ Ql,
    const __bf16* __restrict__ Kh, const __bf16* __restrict__ Kl,
    const __bf16* __restrict__ Vh, const __bf16* __restrict__ Vl,
    const float* __restrict__ G,
    const unsigned long long* __restrict__ mbits,
    const float* __restrict__ invn,
    const float* __restrict__ gamma, const float* __restrict__ beta,
    __bf16* __restrict__ Oh, __bf16* __restrict__ Ol)
{
    __shared__ __bf16 sw[4][2][16 * 72];   // per-wave score tile, hi/lo
    int blk = blockIdx.x;
    int b = blk >> 9, h = (blk >> 5) & 15, qb = blk & 31;
    int tid = threadIdx.x, lane = tid & 63, wid = tid >> 6;
    int r = lane & 15, kg = lane >> 4;
    int q0 = qb * 64 + wid * 16;
    size_t bh = (size_t)b * Hc + h;
    const __bf16* Qhp = Qh + bh * (Sc * HDc);
    const __bf16* Qlp = Ql + bh * (Sc * HDc);
    const __bf16* Khp = Kh + bh * (Sc * HDc);
    const __bf16* Klp = Kl + bh * (Sc * HDc);
    const __bf16* Vhp = Vh + bh * (HDc * Sc);
    const __bf16* Vlp = Vl + bh * (HDc * Sc);

    // Q fragments held in registers across the whole k loop
    bf16x8 qfh[2], qfl[2];
#pragma unroll
    for (int t = 0; t < 2; ++t) {
        size_t qa = (size_t)(q0 + r) * HDc + t * 32 + kg * 8;
        qfh[t] = *(const bf16x8*)&Qhp[qa];
        qfl[t] = *(const bf16x8*)&Qlp[qa];
    }
    float invr[4];
    const unsigned long long* mrow[4];
#pragma unroll
    for (int j = 0; j < 4; ++j) {
        int q = q0 + kg * 4 + j;
        invr[j] = invn[b * Sc + q];
        mrow[j] = mbits + (size_t)(b * Sc + q) * (Sc / 64);
    }
    float gam[4], bet[4];
#pragma unroll
    for (int n = 0; n < 4; ++n) { gam[n] = gamma[n * 16 + r]; bet[n] = beta[n * 16 + r]; }

    f32x4 oacc[4] = {};
    __bf16* swh = &sw[wid][0][0];
    __bf16* swl = &sw[wid][1][0];

    for (int kt = 0; kt < Sc / 64; ++kt) {
        int k0 = kt * 64;
        // ---- QK^T (3-term split) ----
        f32x4 sc[4];
#pragma unroll
        for (int n = 0; n < 4; ++n) {
            f32x4 s = {0.f, 0.f, 0.f, 0.f};
#pragma unroll
            for (int t = 0; t < 2; ++t) {
                size_t ka = (size_t)(k0 + n * 16 + r) * HDc + t * 32 + kg * 8;
                bf16x8 kfh = *(const bf16x8*)&Khp[ka];
                bf16x8 kfl = *(const bf16x8*)&Klp[ka];
                s = MFMA16(qfl[t], kfh, s);
                s = MFMA16(qfh[t], kfl, s);
                s = MFMA16(qfh[t], kfh, s);
            }
            sc[n] = s;
        }
        // ---- score epilogue: scale, silu, mask, invnorm, -> hi/lo in LDS ----
        unsigned long long mw[4];
#pragma unroll
        for (int j = 0; j < 4; ++j) mw[j] = mrow[j][kt];
#pragma unroll
        for (int n = 0; n < 4; ++n)
#pragma unroll
            for (int j = 0; j < 4; ++j) {
                float x = sc[n][j] * SCALE_C;
                float w = ((mw[j] >> (n * 16 + r)) & 1ULL) ? silu_f(x) * invr[j] : 0.0f;
                __bf16 hi = (__bf16)w;
                __bf16 lo = (__bf16)(w - (float)hi);
                swh[(kg * 4 + j) * 72 + n * 16 + r] = hi;
                swl[(kg * 4 + j) * 72 + n * 16 + r] = lo;
            }
        // wave-local LDS round-trip (compiler inserts lgkmcnt; no barrier needed)
        // ---- PV (3-term split) ----
#pragma unroll
        for (int t2 = 0; t2 < 2; ++t2) {
            bf16x8 wfh = *(const bf16x8*)&swh[r * 72 + t2 * 32 + kg * 8];
            bf16x8 wfl = *(const bf16x8*)&swl[r * 72 + t2 * 32 + kg * 8];
#pragma unroll
            for (int n2 = 0; n2 < 4; ++n2) {
                size_t va = (size_t)(n2 * 16 + r) * Sc + k0 + t2 * 32 + kg * 8;
                bf16x8 vfh = *(const bf16x8*)&Vhp[va];
                bf16x8 vfl = *(const bf16x8*)&Vlp[va];
                oacc[n2] = MFMA16(wfl, vfh, oacc[n2]);
                oacc[n2] = MFMA16(wfh, vfl, oacc[n2]);
                oacc[n2] = MFMA16(wfh, vfh, oacc[n2]);
            }
        }
    }

    // ---- LayerNorm over hd=64 + gate ----
    float sum[4];
#pragma unroll
    for (int j = 0; j < 4; ++j)
        sum[j] = oacc[0][j] + oacc[1][j] + oacc[2][j] + oacc[3][j];
#pragma unroll
    for (int off = 1; off < 16; off <<= 1)
#pragma unroll
        for (int j = 0; j < 4; ++j) sum[j] += __shfl_xor(sum[j], off, 64);
    float mean[4], vs[4];
#pragma unroll
    for (int j = 0; j < 4; ++j) mean[j] = sum[j] * (1.0f / 64.0f);
#pragma unroll
    for (int j = 0; j < 4; ++j) {
        float a = 0.f;
#pragma unroll
        for (int n2 = 0; n2 < 4; ++n2) {
            float dlt = oacc[n2][j] - mean[j];
            a += dlt * dlt;
        }
        vs[j] = a;
    }
#pragma unroll
    for (int off = 1; off < 16; off <<= 1)
#pragma unroll
        for (int j = 0; j < 4; ++j) vs[j] += __shfl_xor(vs[j], off, 64);
    float rstd[4];
#pragma unroll
    for (int j = 0; j < 4; ++j) rstd[j] = rsqrtf(vs[j] * (1.0f / 64.0f) + LN_EPS_C);

#pragma unroll
    for (int n2 = 0; n2 < 4; ++n2)
#pragma unroll
        for (int j = 0; j < 4; ++j) {
            int q = q0 + kg * 4 + j;
            int d = n2 * 16 + r;
            float x = (oacc[n2][j] - mean[j]) * rstd[j] * gam[n2] + bet[n2];
            size_t o = (size_t)(b * Sc + q) * Dc + h * HDc + d;
            float res = x * G[o];
            __bf16 hi = (__bf16)res;
            __bf16 lo = (__bf16)(res - (float)hi);
            Oh[o] = hi; Ol[o] = lo;
        }
}

// ---------------------------------------------------------------------------
extern "C" void kernel_launch(void* const* d_in, const int* in_sizes, int n_in,
                              void* d_out, int out_size, void* d_ws, size_t ws_size,
                              hipStream_t stream)
{
    const float* tokens = (const float*)d_in[0];
    const int*   maskp  = (const int*)d_in[1];
    const float* Wqkuv  = (const float*)d_in[2];
    const float* Wout   = (const float*)d_in[3];
    const float* gamma  = (const float*)d_in[4];
    const float* beta   = (const float*)d_in[5];
    float* out = (float*)d_out;

    char* ws = (char*)d_ws;
    size_t off = 0;
    auto alloc = [&](size_t bytes) -> void* {
        void* p = ws + off;
        off = (off + bytes + 255) & ~(size_t)255;
        return p;
    };
    const size_t MK   = (size_t)4096 * 1024;   // tokens / per-tensor elems
    __bf16* Xhi  = (__bf16*)alloc(MK * 2);
    __bf16* Xlo  = (__bf16*)alloc(MK * 2);
    __bf16* Wqth = (__bf16*)alloc((size_t)4096 * 1024 * 2);
    __bf16* Wqtl = (__bf16*)alloc((size_t)4096 * 1024 * 2);
    __bf16* Woth = (__bf16*)alloc((size_t)1024 * 1024 * 2);
    __bf16* Wotl = (__bf16*)alloc((size_t)1024 * 1024 * 2);
    __bf16* Qhp  = (__bf16*)alloc(MK * 2);
    __bf16* Qlp  = (__bf16*)alloc(MK * 2);
    __bf16* Khp  = (__bf16*)alloc(MK * 2);
    __bf16* Klp  = (__bf16*)alloc(MK * 2);
    __bf16* Vhp  = (__bf16*)alloc(MK * 2);
    __bf16* Vlp  = (__bf16*)alloc(MK * 2);
    float*  Gp   = (float*)alloc(MK * 4);
    __bf16* Ohp  = (__bf16*)alloc(MK * 2);
    __bf16* Olp  = (__bf16*)alloc(MK * 2);
    float*  invn = (float*)alloc((size_t)4096 * 4);
    unsigned long long* mbits = (unsigned long long*)alloc((size_t)4096 * 32 * 8);

    // 1. split tokens into hi/lo bf16
    convert_split_kernel<<<(int)(MK / 4 / 256), 256, 0, stream>>>(tokens, Xhi, Xlo, (int)(MK / 4));
    // 2. transpose+split weights (so GEMM B operand is K-contiguous)
    transpose_split_kernel<<<dim3(16, 64), 256, 0, stream>>>(Wqkuv, Wqth, Wqtl, 1024, 4096);
    transpose_split_kernel<<<dim3(16, 16), 256, 0, stream>>>(Wout,  Woth, Wotl, 1024, 1024);
    // 3. mask -> bits + invnorm
    mask_prep_kernel<<<1024, 256, 0, stream>>>(maskp, mbits, invn);
    // 4. proj = silu(X @ W_qkuv), scattered to Q/K/V^T/G
    gemm_split_kernel<0><<<dim3(32, 32), 256, 0, stream>>>(
        Xhi, Xlo, Wqth, Wqtl, 1024, nullptr,
        Qhp, Qlp, Khp, Klp, Vhp, Vlp, Gp);
    // 5. fused attention + LN + gate
    attn_kernel<<<1024, 256, 0, stream>>>(
        Qhp, Qlp, Khp, Klp, Vhp, Vlp, Gp, mbits, invn, gamma, beta, Ohp, Olp);
    // 6. out = attn @ W_out
    gemm_split_kernel<1><<<dim3(32, 8), 256, 0, stream>>>(
        Ohp, Olp, Woth, Wotl, 1024, out,
        nullptr, nullptr, nullptr, nullptr, nullptr, nullptr, nullptr);
}

// Round 7
// 513.295 us; speedup vs baseline: 1.7503x; 1.7503x over previous
//
#include <hip/hip_runtime.h>
#include <math.h>

// ---------------------------------------------------------------------------
// HybridSiLUGatedAttention on MI355X (gfx950)
// B=2, S=2048, D=1024, H=16, hd=64.
// Split-bf16 (hi/lo) 3-term MFMA emulation everywhere (near-fp32 accuracy).
// Round 7: bisection — round-1's PASSING attention compute core VERBATIM
// (16 q-rows/wave, single 64-key P round-trip, unswapped PV, same LN/store),
// with exactly one change: K/V fragments read from block-shared LDS tiles
// (staged via the gemm-validated reg->ds_write->__syncthreads pattern)
// instead of per-wave global loads. 4x K/V traffic cut, no new race surface.
// ---------------------------------------------------------------------------

typedef __bf16 bf16x8 __attribute__((ext_vector_type(8)));
typedef __bf16 bf16x4 __attribute__((ext_vector_type(4)));
typedef float  f32x4  __attribute__((ext_vector_type(4)));

#define MFMA16(A, B, C) __builtin_amdgcn_mfma_f32_16x16x32_bf16((A), (B), (C), 0, 0, 0)

constexpr int   Sc   = 2048;
constexpr int   Dc   = 1024;
constexpr int   Hc   = 16;
constexpr int   HDc  = 64;
constexpr float SCALE_C = 0.125f;   // 1/sqrt(64)
constexpr float LN_EPS_C = 1e-5f;

__device__ __forceinline__ float silu_f(float x) {
    return x / (1.0f + __expf(-x));
}

// --------------------------- elementwise fp32 -> hi/lo bf16 ----------------
__global__ __launch_bounds__(256) void convert_split_kernel(
    const float* __restrict__ X, __bf16* __restrict__ Hi, __bf16* __restrict__ Lo, int n4)
{
    int i = blockIdx.x * 256 + threadIdx.x;
    if (i >= n4) return;
    float4 v = ((const float4*)X)[i];
    float vv[4] = {v.x, v.y, v.z, v.w};
    bf16x4 h, l;
#pragma unroll
    for (int e = 0; e < 4; ++e) {
        __bf16 hh = (__bf16)vv[e];
        h[e] = hh;
        l[e] = (__bf16)(vv[e] - (float)hh);
    }
    ((bf16x4*)Hi)[i] = h;
    ((bf16x4*)Lo)[i] = l;
}

// ------------------- transpose W[K][N] -> T[N][K], split hi/lo -------------
__global__ __launch_bounds__(256) void transpose_split_kernel(
    const float* __restrict__ W, __bf16* __restrict__ Thi, __bf16* __restrict__ Tlo,
    int K, int N)
{
    __shared__ float tile[64][65];
    int kb = blockIdx.x * 64, nb = blockIdx.y * 64;
    int t = threadIdx.x;
    int i  = t >> 2;            // 0..63
    int c0 = (t & 3) * 16;      // 0,16,32,48
    const float* src = W + (size_t)(kb + i) * N + nb + c0;
#pragma unroll
    for (int e = 0; e < 4; ++e) {
        float4 v = ((const float4*)src)[e];
        tile[i][c0 + e * 4 + 0] = v.x;
        tile[i][c0 + e * 4 + 1] = v.y;
        tile[i][c0 + e * 4 + 2] = v.z;
        tile[i][c0 + e * 4 + 3] = v.w;
    }
    __syncthreads();
    int j = i;  // n-offset
#pragma unroll
    for (int e = 0; e < 4; ++e) {
        bf16x4 h, l;
#pragma unroll
        for (int u = 0; u < 4; ++u) {
            float x = tile[c0 + e * 4 + u][j];
            __bf16 hh = (__bf16)x;
            h[u] = hh;
            l[u] = (__bf16)(x - (float)hh);
        }
        size_t o = (size_t)(nb + j) * K + kb + c0 + e * 4;
        *(bf16x4*)&Thi[o] = h;
        *(bf16x4*)&Tlo[o] = l;
    }
}

// -------- mask [B,1,S,S] -> row bit-pack [row][S/64] + invnorm -------------
__global__ __launch_bounds__(256) void mask_prep_kernel(
    const int* __restrict__ mask, unsigned long long* __restrict__ bits,
    float* __restrict__ invn)
{
    int lane = threadIdx.x & 63, wid = threadIdx.x >> 6;
    int row = blockIdx.x * 4 + wid;          // 0..4095  (= b*2048+q)
    const int* mr = mask + (size_t)row * Sc;
    int cnt = 0;
    for (int t = 0; t < Sc / 64; ++t) {
        int m = mr[t * 64 + lane];
        unsigned long long w = __ballot(m != 0);
        if (lane == 0) bits[(size_t)row * (Sc / 64) + t] = w;
        cnt += (int)__popcll(w);
    }
    if (lane == 0) invn[row] = rsqrtf(fmaxf((float)cnt, 1.0f));
}

// --------------------------- split-bf16 GEMM -------------------------------
// C[M][N] = A[M][K] * B^T[N][K]   (both operands stored K-contiguous)
// EPI==0: silu epilogue, scatter to Q/K/V(t)/G (unswizzled, r1-verified).
// EPI==1: plain fp32 out (N=1024).
template<int EPI>
__global__ __launch_bounds__(256) void gemm_split_kernel(
    const __bf16* __restrict__ Ah, const __bf16* __restrict__ Al,
    const __bf16* __restrict__ Bh, const __bf16* __restrict__ Bl,
    int Kdim,
    float* __restrict__ outF,
    __bf16* __restrict__ Qh, __bf16* __restrict__ Ql,
    __bf16* __restrict__ Kh, __bf16* __restrict__ Kl,
    __bf16* __restrict__ Vh, __bf16* __restrict__ Vl,
    float* __restrict__ G)
{
    constexpr int LSTR = 40;               // padded LDS row (bf16)
    __shared__ __bf16 sA[2][128 * LSTR];
    __shared__ __bf16 sB[2][128 * LSTR];
    int tid = threadIdx.x, lane = tid & 63, wid = tid >> 6;
    int r = lane & 15, kg = lane >> 4;
    int wm = wid >> 1, wn = wid & 1;
    int m0 = blockIdx.x * 128, n0 = blockIdx.y * 128;
    int c1r = tid >> 2;                    // 0..63
    int ck  = (tid & 3) * 8;               // 0,8,16,24
    int c2r = c1r + 64;

    f32x4 acc[4][4] = {};

    for (int kt = 0; kt < Kdim; kt += 32) {
        *(bf16x8*)&sA[0][c1r * LSTR + ck] = *(const bf16x8*)&Ah[(size_t)(m0 + c1r) * Kdim + kt + ck];
        *(bf16x8*)&sA[0][c2r * LSTR + ck] = *(const bf16x8*)&Ah[(size_t)(m0 + c2r) * Kdim + kt + ck];
        *(bf16x8*)&sA[1][c1r * LSTR + ck] = *(const bf16x8*)&Al[(size_t)(m0 + c1r) * Kdim + kt + ck];
        *(bf16x8*)&sA[1][c2r * LSTR + ck] = *(const bf16x8*)&Al[(size_t)(m0 + c2r) * Kdim + kt + ck];
        *(bf16x8*)&sB[0][c1r * LSTR + ck] = *(const bf16x8*)&Bh[(size_t)(n0 + c1r) * Kdim + kt + ck];
        *(bf16x8*)&sB[0][c2r * LSTR + ck] = *(const bf16x8*)&Bh[(size_t)(n0 + c2r) * Kdim + kt + ck];
        *(bf16x8*)&sB[1][c1r * LSTR + ck] = *(const bf16x8*)&Bl[(size_t)(n0 + c1r) * Kdim + kt + ck];
        *(bf16x8*)&sB[1][c2r * LSTR + ck] = *(const bf16x8*)&Bl[(size_t)(n0 + c2r) * Kdim + kt + ck];
        __syncthreads();

        bf16x8 afh[4], afl[4], bfh[4], bfl[4];
#pragma unroll
        for (int m = 0; m < 4; ++m) {
            int row = wm * 64 + m * 16 + r;
            afh[m] = *(bf16x8*)&sA[0][row * LSTR + kg * 8];
            afl[m] = *(bf16x8*)&sA[1][row * LSTR + kg * 8];
        }
#pragma unroll
        for (int n = 0; n < 4; ++n) {
            int col = wn * 64 + n * 16 + r;
            bfh[n] = *(bf16x8*)&sB[0][col * LSTR + kg * 8];
            bfl[n] = *(bf16x8*)&sB[1][col * LSTR + kg * 8];
        }
#pragma unroll
        for (int m = 0; m < 4; ++m)
#pragma unroll
            for (int n = 0; n < 4; ++n) {
                acc[m][n] = MFMA16(afl[m], bfh[n], acc[m][n]);
                acc[m][n] = MFMA16(afh[m], bfl[n], acc[m][n]);
                acc[m][n] = MFMA16(afh[m], bfh[n], acc[m][n]);
            }
        __syncthreads();
    }

    int sec = n0 >> 10;  // tile-uniform: 0=q 1=k 2=v 3=g (128 | 1024)
#pragma unroll
    for (int m = 0; m < 4; ++m)
#pragma unroll
        for (int n = 0; n < 4; ++n)
#pragma unroll
            for (int j = 0; j < 4; ++j) {
                int gm = m0 + wm * 64 + m * 16 + kg * 4 + j;   // token row
                int gn = n0 + wn * 64 + n * 16 + r;            // feature col
                float x = acc[m][n][j];
                if constexpr (EPI == 1) {
                    outF[(size_t)gm * 1024 + gn] = x;
                } else {
                    float p = silu_f(x);
                    if (sec == 3) {
                        G[(size_t)gm * Dc + (gn & 1023)] = p;
                    } else {
                        int f = gn & 1023, hd = f >> 6, d = f & 63;
                        int bb = gm >> 11, s = gm & 2047;
                        __bf16 hi = (__bf16)p;
                        __bf16 lo = (__bf16)(p - (float)hi);
                        if (sec == 0) {
                            size_t idx = ((size_t)(bb * Hc + hd) * Sc + s) * HDc + d;
                            Qh[idx] = hi; Ql[idx] = lo;
                        } else if (sec == 1) {
                            size_t idx = ((size_t)(bb * Hc + hd) * Sc + s) * HDc + d;
                            Kh[idx] = hi; Kl[idx] = lo;
                        } else {  // v stored transposed: [b,h,d,s]
                            size_t idx = ((size_t)(bb * Hc + hd) * HDc + d) * Sc + s;
                            Vh[idx] = hi; Vl[idx] = lo;
                        }
                    }
                }
            }
}

// --------------------------- fused attention v4 ----------------------------
// ROUND-1 COMPUTE CORE VERBATIM (grid 1024: b,h,qb of 64 rows; 4 waves x
// 16 q-rows; single 64-key P round-trip per tile; PV with A=P-frag,B=V^T).
// Only change: K/V fragments come from block-shared LDS tiles staged with
// the gemm-validated reg->ds_write->__syncthreads pattern (+reg prefetch).
__global__ __launch_bounds__(256) void attn4_kernel(
    const __bf16* __restrict__ Qh, const __bf16* __restrict__ Ql,
    const __bf16* __restrict__ Kh, const __bf16* __restrict__ Kl,
    const __bf16* __restrict__ Vh, const __bf16* __restrict__ Vl,
    const float* __restrict__ G,
    const unsigned long long* __restrict__ mbits,
    const float* __restrict__ invn,
    const float* __restrict__ gamma, const float* __restrict__ beta,
    __bf16* __restrict__ Oh, __bf16* __restrict__ Ol)
{
    __shared__ __bf16 sKt[2][64 * 72];     // [hi/lo][key][d]   144B rows
    __shared__ __bf16 sVt[2][64 * 72];     // [hi/lo][d][key]
    __shared__ __bf16 sw[4][2][16 * 72];   // r1: per-wave score tile, hi/lo

    int blk = blockIdx.x;
    int b = blk >> 9, h = (blk >> 5) & 15, qb = blk & 31;
    int tid = threadIdx.x, lane = tid & 63, wid = tid >> 6;
    int r = lane & 15, kg = lane >> 4;
    int q0 = qb * 64 + wid * 16;
    size_t bh = (size_t)b * Hc + h;
    const __bf16* Qhp = Qh + bh * (Sc * HDc);
    const __bf16* Qlp = Ql + bh * (Sc * HDc);
    const __bf16* Khp = Kh + bh * (Sc * HDc);
    const __bf16* Klp = Kl + bh * (Sc * HDc);
    const __bf16* Vhp = Vh + bh * (HDc * Sc);
    const __bf16* Vlp = Vl + bh * (HDc * Sc);

    // Q fragments held in registers across the whole k loop (r1 verbatim)
    bf16x8 qfh[2], qfl[2];
#pragma unroll
    for (int t = 0; t < 2; ++t) {
        size_t qa = (size_t)(q0 + r) * HDc + t * 32 + kg * 8;
        qfh[t] = *(const bf16x8*)&Qhp[qa];
        qfl[t] = *(const bf16x8*)&Qlp[qa];
    }
    float invr[4];
    const unsigned long long* mrow[4];
#pragma unroll
    for (int j = 0; j < 4; ++j) {
        int q = q0 + kg * 4 + j;
        invr[j] = invn[b * Sc + q];
        mrow[j] = mbits + (size_t)(b * Sc + q) * (Sc / 64);
    }
    float gam[4], bet[4];
#pragma unroll
    for (int n = 0; n < 4; ++n) { gam[n] = gamma[n * 16 + r]; bet[n] = beta[n * 16 + r]; }

    f32x4 oacc[4] = {};
    __bf16* swh = &sw[wid][0][0];
    __bf16* swl = &sw[wid][1][0];

    // ---- staging setup: thread t covers row sr=t>>2, 16 cols at sc0 ----
    int sr  = tid >> 2;                 // 0..63
    int sc0 = (tid & 3) * 16;           // 0,16,32,48
    const __bf16* gKh = Khp + (size_t)sr * HDc + sc0;   // + k0*HDc
    const __bf16* gKl = Klp + (size_t)sr * HDc + sc0;
    const __bf16* gVh = Vhp + (size_t)sr * Sc + sc0;    // + k0
    const __bf16* gVl = Vlp + (size_t)sr * Sc + sc0;

    bf16x8 rKh[2], rKl[2], rVh[2], rVl[2];
    auto LOADT = [&](int kt) {
        int k0 = kt * 64;
#pragma unroll
        for (int c = 0; c < 2; ++c) {
            rKh[c] = *(const bf16x8*)&gKh[(size_t)k0 * HDc + c * 8];
            rKl[c] = *(const bf16x8*)&gKl[(size_t)k0 * HDc + c * 8];
            rVh[c] = *(const bf16x8*)&gVh[k0 + c * 8];
            rVl[c] = *(const bf16x8*)&gVl[k0 + c * 8];
        }
    };
    auto WRITET = [&]() {
#pragma unroll
        for (int c = 0; c < 2; ++c) {
            *(bf16x8*)&sKt[0][sr * 72 + sc0 + c * 8] = rKh[c];
            *(bf16x8*)&sKt[1][sr * 72 + sc0 + c * 8] = rKl[c];
            *(bf16x8*)&sVt[0][sr * 72 + sc0 + c * 8] = rVh[c];
            *(bf16x8*)&sVt[1][sr * 72 + sc0 + c * 8] = rVl[c];
        }
    };

    LOADT(0);

    for (int kt = 0; kt < Sc / 64; ++kt) {
        if (kt) __syncthreads();    // all reads of previous tile retired
        WRITET();
        __syncthreads();            // tile visible to all waves
        if (kt < 31) LOADT(kt + 1); // prefetch next tile (regs only)

        // ---- QK^T (3-term split) — r1 verbatim, K from LDS ----
        f32x4 sc[4];
#pragma unroll
        for (int n = 0; n < 4; ++n) {
            f32x4 s = {0.f, 0.f, 0.f, 0.f};
#pragma unroll
            for (int t = 0; t < 2; ++t) {
                int ka = (n * 16 + r) * 72 + t * 32 + kg * 8;
                bf16x8 kfh = *(const bf16x8*)&sKt[0][ka];
                bf16x8 kfl = *(const bf16x8*)&sKt[1][ka];
                s = MFMA16(qfl[t], kfh, s);
                s = MFMA16(qfh[t], kfl, s);
                s = MFMA16(qfh[t], kfh, s);
            }
            sc[n] = s;
        }
        // ---- score epilogue — r1 verbatim ----
        unsigned long long mw[4];
#pragma unroll
        for (int j = 0; j < 4; ++j) mw[j] = mrow[j][kt];
#pragma unroll
        for (int n = 0; n < 4; ++n)
#pragma unroll
            for (int j = 0; j < 4; ++j) {
                float x = sc[n][j] * SCALE_C;
                float w = ((mw[j] >> (n * 16 + r)) & 1ULL) ? silu_f(x) * invr[j] : 0.0f;
                __bf16 hi = (__bf16)w;
                __bf16 lo = (__bf16)(w - (float)hi);
                swh[(kg * 4 + j) * 72 + n * 16 + r] = hi;
                swl[(kg * 4 + j) * 72 + n * 16 + r] = lo;
            }
        // wave-local LDS round-trip (r1 verbatim)
        // ---- PV (3-term split) — r1 verbatim, V from LDS ----
#pragma unroll
        for (int t2 = 0; t2 < 2; ++t2) {
            bf16x8 wfh = *(const bf16x8*)&swh[r * 72 + t2 * 32 + kg * 8];
            bf16x8 wfl = *(const bf16x8*)&swl[r * 72 + t2 * 32 + kg * 8];
#pragma unroll
            for (int n2 = 0; n2 < 4; ++n2) {
                int va = (n2 * 16 + r) * 72 + t2 * 32 + kg * 8;
                bf16x8 vfh = *(const bf16x8*)&sVt[0][va];
                bf16x8 vfl = *(const bf16x8*)&sVt[1][va];
                oacc[n2] = MFMA16(wfl, vfh, oacc[n2]);
                oacc[n2] = MFMA16(wfh, vfl, oacc[n2]);
                oacc[n2] = MFMA16(wfh, vfh, oacc[n2]);
            }
        }
    }

    // ---- LayerNorm over hd=64 + gate — r1 verbatim ----
    float sum[4];
#pragma unroll
    for (int j = 0; j < 4; ++j)
        sum[j] = oacc[0][j] + oacc[1][j] + oacc[2][j] + oacc[3][j];
#pragma unroll
    for (int off = 1; off < 16; off <<= 1)
#pragma unroll
        for (int j = 0; j < 4; ++j) sum[j] += __shfl_xor(sum[j], off, 64);
    float mean[4], vs[4];
#pragma unroll
    for (int j = 0; j < 4; ++j) mean[j] = sum[j] * (1.0f / 64.0f);
#pragma unroll
    for (int j = 0; j < 4; ++j) {
        float a = 0.f;
#pragma unroll
        for (int n2 = 0; n2 < 4; ++n2) {
            float dlt = oacc[n2][j] - mean[j];
            a += dlt * dlt;
        }
        vs[j] = a;
    }
#pragma unroll
    for (int off = 1; off < 16; off <<= 1)
#pragma unroll
        for (int j = 0; j < 4; ++j) vs[j] += __shfl_xor(vs[j], off, 64);
    float rstd[4];
#pragma unroll
    for (int j = 0; j < 4; ++j) rstd[j] = rsqrtf(vs[j] * (1.0f / 64.0f) + LN_EPS_C);

#pragma unroll
    for (int n2 = 0; n2 < 4; ++n2)
#pragma unroll
        for (int j = 0; j < 4; ++j) {
            int q = q0 + kg * 4 + j;
            int d = n2 * 16 + r;
            float x = (oacc[n2][j] - mean[j]) * rstd[j] * gam[n2] + bet[n2];
            size_t o = (size_t)(b * Sc + q) * Dc + h * HDc + d;
            float res = x * G[o];
            __bf16 hi = (__bf16)res;
            __bf16 lo = (__bf16)(res - (float)hi);
            Oh[o] = hi; Ol[o] = lo;
        }
}

// ---------------------------------------------------------------------------
extern "C" void kernel_launch(void* const* d_in, const int* in_sizes, int n_in,
                              void* d_out, int out_size, void* d_ws, size_t ws_size,
                              hipStream_t stream)
{
    const float* tokens = (const float*)d_in[0];
    const int*   maskp  = (const int*)d_in[1];
    const float* Wqkuv  = (const float*)d_in[2];
    const float* Wout   = (const float*)d_in[3];
    const float* gamma  = (const float*)d_in[4];
    const float* beta   = (const float*)d_in[5];
    float* out = (float*)d_out;

    char* ws = (char*)d_ws;
    size_t off = 0;
    auto alloc = [&](size_t bytes) -> void* {
        void* p = ws + off;
        off = (off + bytes + 255) & ~(size_t)255;
        return p;
    };
    const size_t MK = (size_t)4096 * 1024;
    __bf16* Xhi  = (__bf16*)alloc(MK * 2);
    __bf16* Xlo  = (__bf16*)alloc(MK * 2);
    __bf16* Wqth = (__bf16*)alloc((size_t)4096 * 1024 * 2);
    __bf16* Wqtl = (__bf16*)alloc((size_t)4096 * 1024 * 2);
    __bf16* Woth = (__bf16*)alloc((size_t)1024 * 1024 * 2);
    __bf16* Wotl = (__bf16*)alloc((size_t)1024 * 1024 * 2);
    __bf16* Qhp  = (__bf16*)alloc(MK * 2);
    __bf16* Qlp  = (__bf16*)alloc(MK * 2);
    __bf16* Khp  = (__bf16*)alloc(MK * 2);
    __bf16* Klp  = (__bf16*)alloc(MK * 2);
    __bf16* Vhp  = (__bf16*)alloc(MK * 2);
    __bf16* Vlp  = (__bf16*)alloc(MK * 2);
    float*  Gp   = (float*)alloc(MK * 4);
    __bf16* Ohp  = (__bf16*)alloc(MK * 2);
    __bf16* Olp  = (__bf16*)alloc(MK * 2);
    float*  invn = (float*)alloc((size_t)4096 * 4);
    unsigned long long* mbits = (unsigned long long*)alloc((size_t)4096 * 32 * 8);

    convert_split_kernel<<<(int)(MK / 4 / 256), 256, 0, stream>>>(tokens, Xhi, Xlo, (int)(MK / 4));
    transpose_split_kernel<<<dim3(16, 64), 256, 0, stream>>>(Wqkuv, Wqth, Wqtl, 1024, 4096);
    transpose_split_kernel<<<dim3(16, 16), 256, 0, stream>>>(Wout,  Woth, Wotl, 1024, 1024);
    mask_prep_kernel<<<1024, 256, 0, stream>>>(maskp, mbits, invn);
    gemm_split_kernel<0><<<dim3(32, 32), 256, 0, stream>>>(
        Xhi, Xlo, Wqth, Wqtl, 1024, nullptr,
        Qhp, Qlp, Khp, Klp, Vhp, Vlp, Gp);
    attn4_kernel<<<1024, 256, 0, stream>>>(
        Qhp, Qlp, Khp, Klp, Vhp, Vlp, Gp, mbits, invn, gamma, beta, Ohp, Olp);
    gemm_split_kernel<1><<<dim3(32, 8), 256, 0, stream>>>(
        Ohp, Olp, Woth, Wotl, 1024, out,
        nullptr, nullptr, nullptr, nullptr, nullptr, nullptr, nullptr);
}

// Round 8
// 472.262 us; speedup vs baseline: 1.9024x; 1.0869x over previous
//
#include <hip/hip_runtime.h>
#include <math.h>

// ---------------------------------------------------------------------------
// HybridSiLUGatedAttention on MI355X (gfx950)
// B=2, S=2048, D=1024, H=16, hd=64.
// Split-bf16 (hi/lo) 3-term MFMA emulation everywhere (near-fp32 accuracy).
// Round 8: attention widened to 8 waves / 512 threads / 128 q-rows per block
// (grid 512) with the r7-verified per-wave core VERBATIM. K/V staged once
// per 128 q-rows (was 64) -> staging cost and K/V fetch halved; 16 waves/CU
// (was 8). Bijective XCD swizzle on the 512-block grid. Same two-barrier
// staging protocol. gemm kernels unchanged (next round's target).
// ---------------------------------------------------------------------------

typedef __bf16 bf16x8 __attribute__((ext_vector_type(8)));
typedef __bf16 bf16x4 __attribute__((ext_vector_type(4)));
typedef float  f32x4  __attribute__((ext_vector_type(4)));

#define MFMA16(A, B, C) __builtin_amdgcn_mfma_f32_16x16x32_bf16((A), (B), (C), 0, 0, 0)

constexpr int   Sc   = 2048;
constexpr int   Dc   = 1024;
constexpr int   Hc   = 16;
constexpr int   HDc  = 64;
constexpr float SCALE_C = 0.125f;   // 1/sqrt(64)
constexpr float LN_EPS_C = 1e-5f;

__device__ __forceinline__ float silu_f(float x) {
    return x / (1.0f + __expf(-x));
}

// --------------------------- elementwise fp32 -> hi/lo bf16 ----------------
__global__ __launch_bounds__(256) void convert_split_kernel(
    const float* __restrict__ X, __bf16* __restrict__ Hi, __bf16* __restrict__ Lo, int n4)
{
    int i = blockIdx.x * 256 + threadIdx.x;
    if (i >= n4) return;
    float4 v = ((const float4*)X)[i];
    float vv[4] = {v.x, v.y, v.z, v.w};
    bf16x4 h, l;
#pragma unroll
    for (int e = 0; e < 4; ++e) {
        __bf16 hh = (__bf16)vv[e];
        h[e] = hh;
        l[e] = (__bf16)(vv[e] - (float)hh);
    }
    ((bf16x4*)Hi)[i] = h;
    ((bf16x4*)Lo)[i] = l;
}

// ------------------- transpose W[K][N] -> T[N][K], split hi/lo -------------
__global__ __launch_bounds__(256) void transpose_split_kernel(
    const float* __restrict__ W, __bf16* __restrict__ Thi, __bf16* __restrict__ Tlo,
    int K, int N)
{
    __shared__ float tile[64][65];
    int kb = blockIdx.x * 64, nb = blockIdx.y * 64;
    int t = threadIdx.x;
    int i  = t >> 2;            // 0..63
    int c0 = (t & 3) * 16;      // 0,16,32,48
    const float* src = W + (size_t)(kb + i) * N + nb + c0;
#pragma unroll
    for (int e = 0; e < 4; ++e) {
        float4 v = ((const float4*)src)[e];
        tile[i][c0 + e * 4 + 0] = v.x;
        tile[i][c0 + e * 4 + 1] = v.y;
        tile[i][c0 + e * 4 + 2] = v.z;
        tile[i][c0 + e * 4 + 3] = v.w;
    }
    __syncthreads();
    int j = i;  // n-offset
#pragma unroll
    for (int e = 0; e < 4; ++e) {
        bf16x4 h, l;
#pragma unroll
        for (int u = 0; u < 4; ++u) {
            float x = tile[c0 + e * 4 + u][j];
            __bf16 hh = (__bf16)x;
            h[u] = hh;
            l[u] = (__bf16)(x - (float)hh);
        }
        size_t o = (size_t)(nb + j) * K + kb + c0 + e * 4;
        *(bf16x4*)&Thi[o] = h;
        *(bf16x4*)&Tlo[o] = l;
    }
}

// -------- mask [B,1,S,S] -> row bit-pack [row][S/64] + invnorm -------------
__global__ __launch_bounds__(256) void mask_prep_kernel(
    const int* __restrict__ mask, unsigned long long* __restrict__ bits,
    float* __restrict__ invn)
{
    int lane = threadIdx.x & 63, wid = threadIdx.x >> 6;
    int row = blockIdx.x * 4 + wid;          // 0..4095  (= b*2048+q)
    const int* mr = mask + (size_t)row * Sc;
    int cnt = 0;
    for (int t = 0; t < Sc / 64; ++t) {
        int m = mr[t * 64 + lane];
        unsigned long long w = __ballot(m != 0);
        if (lane == 0) bits[(size_t)row * (Sc / 64) + t] = w;
        cnt += (int)__popcll(w);
    }
    if (lane == 0) invn[row] = rsqrtf(fmaxf((float)cnt, 1.0f));
}

// --------------------------- split-bf16 GEMM -------------------------------
// C[M][N] = A[M][K] * B^T[N][K]   (both operands stored K-contiguous)
// EPI==0: silu epilogue, scatter to Q/K/V(t)/G (unswizzled, r1-verified).
// EPI==1: plain fp32 out (N=1024).
template<int EPI>
__global__ __launch_bounds__(256) void gemm_split_kernel(
    const __bf16* __restrict__ Ah, const __bf16* __restrict__ Al,
    const __bf16* __restrict__ Bh, const __bf16* __restrict__ Bl,
    int Kdim,
    float* __restrict__ outF,
    __bf16* __restrict__ Qh, __bf16* __restrict__ Ql,
    __bf16* __restrict__ Kh, __bf16* __restrict__ Kl,
    __bf16* __restrict__ Vh, __bf16* __restrict__ Vl,
    float* __restrict__ G)
{
    constexpr int LSTR = 40;               // padded LDS row (bf16)
    __shared__ __bf16 sA[2][128 * LSTR];
    __shared__ __bf16 sB[2][128 * LSTR];
    int tid = threadIdx.x, lane = tid & 63, wid = tid >> 6;
    int r = lane & 15, kg = lane >> 4;
    int wm = wid >> 1, wn = wid & 1;
    int m0 = blockIdx.x * 128, n0 = blockIdx.y * 128;
    int c1r = tid >> 2;                    // 0..63
    int ck  = (tid & 3) * 8;               // 0,8,16,24
    int c2r = c1r + 64;

    f32x4 acc[4][4] = {};

    for (int kt = 0; kt < Kdim; kt += 32) {
        *(bf16x8*)&sA[0][c1r * LSTR + ck] = *(const bf16x8*)&Ah[(size_t)(m0 + c1r) * Kdim + kt + ck];
        *(bf16x8*)&sA[0][c2r * LSTR + ck] = *(const bf16x8*)&Ah[(size_t)(m0 + c2r) * Kdim + kt + ck];
        *(bf16x8*)&sA[1][c1r * LSTR + ck] = *(const bf16x8*)&Al[(size_t)(m0 + c1r) * Kdim + kt + ck];
        *(bf16x8*)&sA[1][c2r * LSTR + ck] = *(const bf16x8*)&Al[(size_t)(m0 + c2r) * Kdim + kt + ck];
        *(bf16x8*)&sB[0][c1r * LSTR + ck] = *(const bf16x8*)&Bh[(size_t)(n0 + c1r) * Kdim + kt + ck];
        *(bf16x8*)&sB[0][c2r * LSTR + ck] = *(const bf16x8*)&Bh[(size_t)(n0 + c2r) * Kdim + kt + ck];
        *(bf16x8*)&sB[1][c1r * LSTR + ck] = *(const bf16x8*)&Bl[(size_t)(n0 + c1r) * Kdim + kt + ck];
        *(bf16x8*)&sB[1][c2r * LSTR + ck] = *(const bf16x8*)&Bl[(size_t)(n0 + c2r) * Kdim + kt + ck];
        __syncthreads();

        bf16x8 afh[4], afl[4], bfh[4], bfl[4];
#pragma unroll
        for (int m = 0; m < 4; ++m) {
            int row = wm * 64 + m * 16 + r;
            afh[m] = *(bf16x8*)&sA[0][row * LSTR + kg * 8];
            afl[m] = *(bf16x8*)&sA[1][row * LSTR + kg * 8];
        }
#pragma unroll
        for (int n = 0; n < 4; ++n) {
            int col = wn * 64 + n * 16 + r;
            bfh[n] = *(bf16x8*)&sB[0][col * LSTR + kg * 8];
            bfl[n] = *(bf16x8*)&sB[1][col * LSTR + kg * 8];
        }
#pragma unroll
        for (int m = 0; m < 4; ++m)
#pragma unroll
            for (int n = 0; n < 4; ++n) {
                acc[m][n] = MFMA16(afl[m], bfh[n], acc[m][n]);
                acc[m][n] = MFMA16(afh[m], bfl[n], acc[m][n]);
                acc[m][n] = MFMA16(afh[m], bfh[n], acc[m][n]);
            }
        __syncthreads();
    }

    int sec = n0 >> 10;  // tile-uniform: 0=q 1=k 2=v 3=g (128 | 1024)
#pragma unroll
    for (int m = 0; m < 4; ++m)
#pragma unroll
        for (int n = 0; n < 4; ++n)
#pragma unroll
            for (int j = 0; j < 4; ++j) {
                int gm = m0 + wm * 64 + m * 16 + kg * 4 + j;   // token row
                int gn = n0 + wn * 64 + n * 16 + r;            // feature col
                float x = acc[m][n][j];
                if constexpr (EPI == 1) {
                    outF[(size_t)gm * 1024 + gn] = x;
                } else {
                    float p = silu_f(x);
                    if (sec == 3) {
                        G[(size_t)gm * Dc + (gn & 1023)] = p;
                    } else {
                        int f = gn & 1023, hd = f >> 6, d = f & 63;
                        int bb = gm >> 11, s = gm & 2047;
                        __bf16 hi = (__bf16)p;
                        __bf16 lo = (__bf16)(p - (float)hi);
                        if (sec == 0) {
                            size_t idx = ((size_t)(bb * Hc + hd) * Sc + s) * HDc + d;
                            Qh[idx] = hi; Ql[idx] = lo;
                        } else if (sec == 1) {
                            size_t idx = ((size_t)(bb * Hc + hd) * Sc + s) * HDc + d;
                            Kh[idx] = hi; Kl[idx] = lo;
                        } else {  // v stored transposed: [b,h,d,s]
                            size_t idx = ((size_t)(bb * Hc + hd) * HDc + d) * Sc + s;
                            Vh[idx] = hi; Vl[idx] = lo;
                        }
                    }
                }
            }
}

// --------------------------- fused attention v5 ----------------------------
// grid 512 (XCD-swizzled): b(2) x h(16) x qb(16 tiles of 128 q-rows).
// 512 threads = 8 waves x 16 q-rows — per-wave compute core is r7 VERBATIM.
// K/V (64-key tile) staged once per block via reg->ds_write->__syncthreads.
__global__ __launch_bounds__(512) void attn5_kernel(
    const __bf16* __restrict__ Qh, const __bf16* __restrict__ Ql,
    const __bf16* __restrict__ Kh, const __bf16* __restrict__ Kl,
    const __bf16* __restrict__ Vh, const __bf16* __restrict__ Vl,
    const float* __restrict__ G,
    const unsigned long long* __restrict__ mbits,
    const float* __restrict__ invn,
    const float* __restrict__ gamma, const float* __restrict__ beta,
    __bf16* __restrict__ Oh, __bf16* __restrict__ Ol)
{
    __shared__ __bf16 sKt[2][64 * 72];     // [hi/lo][key][d]   144B rows
    __shared__ __bf16 sVt[2][64 * 72];     // [hi/lo][d][key]
    __shared__ __bf16 sw[8][2][16 * 72];   // per-wave score tile, hi/lo

    // bijective XCD swizzle: 512 = 8 XCDs x 64 consecutive blocks
    int blk = (blockIdx.x & 7) * 64 + (blockIdx.x >> 3);
    int b = blk >> 8, h = (blk >> 4) & 15, qb = blk & 15;
    int tid = threadIdx.x, lane = tid & 63, wid = tid >> 6;   // wid 0..7
    int r = lane & 15, kg = lane >> 4;
    int q0 = qb * 128 + wid * 16;
    size_t bh = (size_t)b * Hc + h;
    const __bf16* Qhp = Qh + bh * (Sc * HDc);
    const __bf16* Qlp = Ql + bh * (Sc * HDc);
    const __bf16* Khp = Kh + bh * (Sc * HDc);
    const __bf16* Klp = Kl + bh * (Sc * HDc);
    const __bf16* Vhp = Vh + bh * (HDc * Sc);
    const __bf16* Vlp = Vl + bh * (HDc * Sc);

    // Q fragments held in registers across the whole k loop (r7 verbatim)
    bf16x8 qfh[2], qfl[2];
#pragma unroll
    for (int t = 0; t < 2; ++t) {
        size_t qa = (size_t)(q0 + r) * HDc + t * 32 + kg * 8;
        qfh[t] = *(const bf16x8*)&Qhp[qa];
        qfl[t] = *(const bf16x8*)&Qlp[qa];
    }
    float invr[4];
    const unsigned long long* mrow[4];
#pragma unroll
    for (int j = 0; j < 4; ++j) {
        int q = q0 + kg * 4 + j;
        invr[j] = invn[b * Sc + q];
        mrow[j] = mbits + (size_t)(b * Sc + q) * (Sc / 64);
    }
    float gam[4], bet[4];
#pragma unroll
    for (int n = 0; n < 4; ++n) { gam[n] = gamma[n * 16 + r]; bet[n] = beta[n * 16 + r]; }

    f32x4 oacc[4] = {};
    __bf16* swh = &sw[wid][0][0];
    __bf16* swl = &sw[wid][1][0];

    // ---- staging: 512 threads cover 64 rows x 64 cols, 8 elems each ----
    int sr  = tid >> 3;                 // 0..63
    int sc0 = (tid & 7) * 8;            // 0,8,..,56
    const __bf16* gKh = Khp + (size_t)sr * HDc + sc0;   // + k0*HDc
    const __bf16* gKl = Klp + (size_t)sr * HDc + sc0;
    const __bf16* gVh = Vhp + (size_t)sr * Sc + sc0;    // + k0
    const __bf16* gVl = Vlp + (size_t)sr * Sc + sc0;

    bf16x8 rKh, rKl, rVh, rVl;
    auto LOADT = [&](int kt) {
        int k0 = kt * 64;
        rKh = *(const bf16x8*)&gKh[(size_t)k0 * HDc];
        rKl = *(const bf16x8*)&gKl[(size_t)k0 * HDc];
        rVh = *(const bf16x8*)&gVh[k0];
        rVl = *(const bf16x8*)&gVl[k0];
    };
    auto WRITET = [&]() {
        *(bf16x8*)&sKt[0][sr * 72 + sc0] = rKh;
        *(bf16x8*)&sKt[1][sr * 72 + sc0] = rKl;
        *(bf16x8*)&sVt[0][sr * 72 + sc0] = rVh;
        *(bf16x8*)&sVt[1][sr * 72 + sc0] = rVl;
    };

    LOADT(0);

    for (int kt = 0; kt < Sc / 64; ++kt) {
        if (kt) __syncthreads();    // all reads of previous tile retired
        WRITET();
        __syncthreads();            // tile visible to all waves
        if (kt < 31) LOADT(kt + 1); // prefetch next tile (regs only)

        // ---- QK^T (3-term split) — r7 verbatim, K from LDS ----
        f32x4 sc[4];
#pragma unroll
        for (int n = 0; n < 4; ++n) {
            f32x4 s = {0.f, 0.f, 0.f, 0.f};
#pragma unroll
            for (int t = 0; t < 2; ++t) {
                int ka = (n * 16 + r) * 72 + t * 32 + kg * 8;
                bf16x8 kfh = *(const bf16x8*)&sKt[0][ka];
                bf16x8 kfl = *(const bf16x8*)&sKt[1][ka];
                s = MFMA16(qfl[t], kfh, s);
                s = MFMA16(qfh[t], kfl, s);
                s = MFMA16(qfh[t], kfh, s);
            }
            sc[n] = s;
        }
        // ---- score epilogue — r7 verbatim ----
        unsigned long long mw[4];
#pragma unroll
        for (int j = 0; j < 4; ++j) mw[j] = mrow[j][kt];
#pragma unroll
        for (int n = 0; n < 4; ++n)
#pragma unroll
            for (int j = 0; j < 4; ++j) {
                float x = sc[n][j] * SCALE_C;
                float w = ((mw[j] >> (n * 16 + r)) & 1ULL) ? silu_f(x) * invr[j] : 0.0f;
                __bf16 hi = (__bf16)w;
                __bf16 lo = (__bf16)(w - (float)hi);
                swh[(kg * 4 + j) * 72 + n * 16 + r] = hi;
                swl[(kg * 4 + j) * 72 + n * 16 + r] = lo;
            }
        // wave-local LDS round-trip (r7 verbatim)
        // ---- PV (3-term split) — r7 verbatim, V from LDS ----
#pragma unroll
        for (int t2 = 0; t2 < 2; ++t2) {
            bf16x8 wfh = *(const bf16x8*)&swh[r * 72 + t2 * 32 + kg * 8];
            bf16x8 wfl = *(const bf16x8*)&swl[r * 72 + t2 * 32 + kg * 8];
#pragma unroll
            for (int n2 = 0; n2 < 4; ++n2) {
                int va = (n2 * 16 + r) * 72 + t2 * 32 + kg * 8;
                bf16x8 vfh = *(const bf16x8*)&sVt[0][va];
                bf16x8 vfl = *(const bf16x8*)&sVt[1][va];
                oacc[n2] = MFMA16(wfl, vfh, oacc[n2]);
                oacc[n2] = MFMA16(wfh, vfl, oacc[n2]);
                oacc[n2] = MFMA16(wfh, vfh, oacc[n2]);
            }
        }
    }

    // ---- LayerNorm over hd=64 + gate — r7 verbatim ----
    float sum[4];
#pragma unroll
    for (int j = 0; j < 4; ++j)
        sum[j] = oacc[0][j] + oacc[1][j] + oacc[2][j] + oacc[3][j];
#pragma unroll
    for (int off = 1; off < 16; off <<= 1)
#pragma unroll
        for (int j = 0; j < 4; ++j) sum[j] += __shfl_xor(sum[j], off, 64);
    float mean[4], vs[4];
#pragma unroll
    for (int j = 0; j < 4; ++j) mean[j] = sum[j] * (1.0f / 64.0f);
#pragma unroll
    for (int j = 0; j < 4; ++j) {
        float a = 0.f;
#pragma unroll
        for (int n2 = 0; n2 < 4; ++n2) {
            float dlt = oacc[n2][j] - mean[j];
            a += dlt * dlt;
        }
        vs[j] = a;
    }
#pragma unroll
    for (int off = 1; off < 16; off <<= 1)
#pragma unroll
        for (int j = 0; j < 4; ++j) vs[j] += __shfl_xor(vs[j], off, 64);
    float rstd[4];
#pragma unroll
    for (int j = 0; j < 4; ++j) rstd[j] = rsqrtf(vs[j] * (1.0f / 64.0f) + LN_EPS_C);

#pragma unroll
    for (int n2 = 0; n2 < 4; ++n2)
#pragma unroll
        for (int j = 0; j < 4; ++j) {
            int q = q0 + kg * 4 + j;
            int d = n2 * 16 + r;
            float x = (oacc[n2][j] - mean[j]) * rstd[j] * gam[n2] + bet[n2];
            size_t o = (size_t)(b * Sc + q) * Dc + h * HDc + d;
            float res = x * G[o];
            __bf16 hi = (__bf16)res;
            __bf16 lo = (__bf16)(res - (float)hi);
            Oh[o] = hi; Ol[o] = lo;
        }
}

// ---------------------------------------------------------------------------
extern "C" void kernel_launch(void* const* d_in, const int* in_sizes, int n_in,
                              void* d_out, int out_size, void* d_ws, size_t ws_size,
                              hipStream_t stream)
{
    const float* tokens = (const float*)d_in[0];
    const int*   maskp  = (const int*)d_in[1];
    const float* Wqkuv  = (const float*)d_in[2];
    const float* Wout   = (const float*)d_in[3];
    const float* gamma  = (const float*)d_in[4];
    const float* beta   = (const float*)d_in[5];
    float* out = (float*)d_out;

    char* ws = (char*)d_ws;
    size_t off = 0;
    auto alloc = [&](size_t bytes) -> void* {
        void* p = ws + off;
        off = (off + bytes + 255) & ~(size_t)255;
        return p;
    };
    const size_t MK = (size_t)4096 * 1024;
    __bf16* Xhi  = (__bf16*)alloc(MK * 2);
    __bf16* Xlo  = (__bf16*)alloc(MK * 2);
    __bf16* Wqth = (__bf16*)alloc((size_t)4096 * 1024 * 2);
    __bf16* Wqtl = (__bf16*)alloc((size_t)4096 * 1024 * 2);
    __bf16* Woth = (__bf16*)alloc((size_t)1024 * 1024 * 2);
    __bf16* Wotl = (__bf16*)alloc((size_t)1024 * 1024 * 2);
    __bf16* Qhp  = (__bf16*)alloc(MK * 2);
    __bf16* Qlp  = (__bf16*)alloc(MK * 2);
    __bf16* Khp  = (__bf16*)alloc(MK * 2);
    __bf16* Klp  = (__bf16*)alloc(MK * 2);
    __bf16* Vhp  = (__bf16*)alloc(MK * 2);
    __bf16* Vlp  = (__bf16*)alloc(MK * 2);
    float*  Gp   = (float*)alloc(MK * 4);
    __bf16* Ohp  = (__bf16*)alloc(MK * 2);
    __bf16* Olp  = (__bf16*)alloc(MK * 2);
    float*  invn = (float*)alloc((size_t)4096 * 4);
    unsigned long long* mbits = (unsigned long long*)alloc((size_t)4096 * 32 * 8);

    convert_split_kernel<<<(int)(MK / 4 / 256), 256, 0, stream>>>(tokens, Xhi, Xlo, (int)(MK / 4));
    transpose_split_kernel<<<dim3(16, 64), 256, 0, stream>>>(Wqkuv, Wqth, Wqtl, 1024, 4096);
    transpose_split_kernel<<<dim3(16, 16), 256, 0, stream>>>(Wout,  Woth, Wotl, 1024, 1024);
    mask_prep_kernel<<<1024, 256, 0, stream>>>(maskp, mbits, invn);
    gemm_split_kernel<0><<<dim3(32, 32), 256, 0, stream>>>(
        Xhi, Xlo, Wqth, Wqtl, 1024, nullptr,
        Qhp, Qlp, Khp, Klp, Vhp, Vlp, Gp);
    attn5_kernel<<<512, 512, 0, stream>>>(
        Qhp, Qlp, Khp, Klp, Vhp, Vlp, Gp, mbits, invn, gamma, beta, Ohp, Olp);
    gemm_split_kernel<1><<<dim3(32, 8), 256, 0, stream>>>(
        Ohp, Olp, Woth, Wotl, 1024, out,
        nullptr, nullptr, nullptr, nullptr, nullptr, nullptr, nullptr);
}

// Round 10
// 439.909 us; speedup vs baseline: 2.0423x; 1.0735x over previous
//
#include <hip/hip_runtime.h>
#include <math.h>

// ---------------------------------------------------------------------------
// HybridSiLUGatedAttention on MI355X (gfx950)
// B=2, S=2048, D=1024, H=16, hd=64.
// Round 10: identical resubmit of round 9 (GPU acquisition timeout; kernel
// never ran). P (scores) and V as SINGLE bf16 (Q/K stay hi/lo -> 3-term
// QK^T); PV 1-term (8 MFMA/tile, was 24); V-lo never staged; LDS 73.7->46.1
// KB -> 3 blocks/CU (24 waves). Error budget ~0.01-0.03 vs 0.073 threshold.
// Structure/sync identical to r8-passing kernel.
// ---------------------------------------------------------------------------

typedef __bf16 bf16x8 __attribute__((ext_vector_type(8)));
typedef __bf16 bf16x4 __attribute__((ext_vector_type(4)));
typedef float  f32x4  __attribute__((ext_vector_type(4)));

#define MFMA16(A, B, C) __builtin_amdgcn_mfma_f32_16x16x32_bf16((A), (B), (C), 0, 0, 0)

constexpr int   Sc   = 2048;
constexpr int   Dc   = 1024;
constexpr int   Hc   = 16;
constexpr int   HDc  = 64;
constexpr float SCALE_C = 0.125f;   // 1/sqrt(64)
constexpr float LN_EPS_C = 1e-5f;

__device__ __forceinline__ float silu_f(float x) {
    return x / (1.0f + __expf(-x));
}

// --------------------------- elementwise fp32 -> hi/lo bf16 ----------------
__global__ __launch_bounds__(256) void convert_split_kernel(
    const float* __restrict__ X, __bf16* __restrict__ Hi, __bf16* __restrict__ Lo, int n4)
{
    int i = blockIdx.x * 256 + threadIdx.x;
    if (i >= n4) return;
    float4 v = ((const float4*)X)[i];
    float vv[4] = {v.x, v.y, v.z, v.w};
    bf16x4 h, l;
#pragma unroll
    for (int e = 0; e < 4; ++e) {
        __bf16 hh = (__bf16)vv[e];
        h[e] = hh;
        l[e] = (__bf16)(vv[e] - (float)hh);
    }
    ((bf16x4*)Hi)[i] = h;
    ((bf16x4*)Lo)[i] = l;
}

// ------------------- transpose W[K][N] -> T[N][K], split hi/lo -------------
__global__ __launch_bounds__(256) void transpose_split_kernel(
    const float* __restrict__ W, __bf16* __restrict__ Thi, __bf16* __restrict__ Tlo,
    int K, int N)
{
    __shared__ float tile[64][65];
    int kb = blockIdx.x * 64, nb = blockIdx.y * 64;
    int t = threadIdx.x;
    int i  = t >> 2;            // 0..63
    int c0 = (t & 3) * 16;      // 0,16,32,48
    const float* src = W + (size_t)(kb + i) * N + nb + c0;
#pragma unroll
    for (int e = 0; e < 4; ++e) {
        float4 v = ((const float4*)src)[e];
        tile[i][c0 + e * 4 + 0] = v.x;
        tile[i][c0 + e * 4 + 1] = v.y;
        tile[i][c0 + e * 4 + 2] = v.z;
        tile[i][c0 + e * 4 + 3] = v.w;
    }
    __syncthreads();
    int j = i;  // n-offset
#pragma unroll
    for (int e = 0; e < 4; ++e) {
        bf16x4 h, l;
#pragma unroll
        for (int u = 0; u < 4; ++u) {
            float x = tile[c0 + e * 4 + u][j];
            __bf16 hh = (__bf16)x;
            h[u] = hh;
            l[u] = (__bf16)(x - (float)hh);
        }
        size_t o = (size_t)(nb + j) * K + kb + c0 + e * 4;
        *(bf16x4*)&Thi[o] = h;
        *(bf16x4*)&Tlo[o] = l;
    }
}

// -------- mask [B,1,S,S] -> row bit-pack [row][S/64] + invnorm -------------
__global__ __launch_bounds__(256) void mask_prep_kernel(
    const int* __restrict__ mask, unsigned long long* __restrict__ bits,
    float* __restrict__ invn)
{
    int lane = threadIdx.x & 63, wid = threadIdx.x >> 6;
    int row = blockIdx.x * 4 + wid;          // 0..4095  (= b*2048+q)
    const int* mr = mask + (size_t)row * Sc;
    int cnt = 0;
    for (int t = 0; t < Sc / 64; ++t) {
        int m = mr[t * 64 + lane];
        unsigned long long w = __ballot(m != 0);
        if (lane == 0) bits[(size_t)row * (Sc / 64) + t] = w;
        cnt += (int)__popcll(w);
    }
    if (lane == 0) invn[row] = rsqrtf(fmaxf((float)cnt, 1.0f));
}

// --------------------------- split-bf16 GEMM -------------------------------
// C[M][N] = A[M][K] * B^T[N][K]   (both operands stored K-contiguous)
// EPI==0: silu epilogue, scatter to Q/K/V(t)/G (unswizzled, r1-verified).
// EPI==1: plain fp32 out (N=1024).
template<int EPI>
__global__ __launch_bounds__(256) void gemm_split_kernel(
    const __bf16* __restrict__ Ah, const __bf16* __restrict__ Al,
    const __bf16* __restrict__ Bh, const __bf16* __restrict__ Bl,
    int Kdim,
    float* __restrict__ outF,
    __bf16* __restrict__ Qh, __bf16* __restrict__ Ql,
    __bf16* __restrict__ Kh, __bf16* __restrict__ Kl,
    __bf16* __restrict__ Vh, __bf16* __restrict__ Vl,
    float* __restrict__ G)
{
    constexpr int LSTR = 40;               // padded LDS row (bf16)
    __shared__ __bf16 sA[2][128 * LSTR];
    __shared__ __bf16 sB[2][128 * LSTR];
    int tid = threadIdx.x, lane = tid & 63, wid = tid >> 6;
    int r = lane & 15, kg = lane >> 4;
    int wm = wid >> 1, wn = wid & 1;
    int m0 = blockIdx.x * 128, n0 = blockIdx.y * 128;
    int c1r = tid >> 2;                    // 0..63
    int ck  = (tid & 3) * 8;               // 0,8,16,24
    int c2r = c1r + 64;

    f32x4 acc[4][4] = {};

    for (int kt = 0; kt < Kdim; kt += 32) {
        *(bf16x8*)&sA[0][c1r * LSTR + ck] = *(const bf16x8*)&Ah[(size_t)(m0 + c1r) * Kdim + kt + ck];
        *(bf16x8*)&sA[0][c2r * LSTR + ck] = *(const bf16x8*)&Ah[(size_t)(m0 + c2r) * Kdim + kt + ck];
        *(bf16x8*)&sA[1][c1r * LSTR + ck] = *(const bf16x8*)&Al[(size_t)(m0 + c1r) * Kdim + kt + ck];
        *(bf16x8*)&sA[1][c2r * LSTR + ck] = *(const bf16x8*)&Al[(size_t)(m0 + c2r) * Kdim + kt + ck];
        *(bf16x8*)&sB[0][c1r * LSTR + ck] = *(const bf16x8*)&Bh[(size_t)(n0 + c1r) * Kdim + kt + ck];
        *(bf16x8*)&sB[0][c2r * LSTR + ck] = *(const bf16x8*)&Bh[(size_t)(n0 + c2r) * Kdim + kt + ck];
        *(bf16x8*)&sB[1][c1r * LSTR + ck] = *(const bf16x8*)&Bl[(size_t)(n0 + c1r) * Kdim + kt + ck];
        *(bf16x8*)&sB[1][c2r * LSTR + ck] = *(const bf16x8*)&Bl[(size_t)(n0 + c2r) * Kdim + kt + ck];
        __syncthreads();

        bf16x8 afh[4], afl[4], bfh[4], bfl[4];
#pragma unroll
        for (int m = 0; m < 4; ++m) {
            int row = wm * 64 + m * 16 + r;
            afh[m] = *(bf16x8*)&sA[0][row * LSTR + kg * 8];
            afl[m] = *(bf16x8*)&sA[1][row * LSTR + kg * 8];
        }
#pragma unroll
        for (int n = 0; n < 4; ++n) {
            int col = wn * 64 + n * 16 + r;
            bfh[n] = *(bf16x8*)&sB[0][col * LSTR + kg * 8];
            bfl[n] = *(bf16x8*)&sB[1][col * LSTR + kg * 8];
        }
#pragma unroll
        for (int m = 0; m < 4; ++m)
#pragma unroll
            for (int n = 0; n < 4; ++n) {
                acc[m][n] = MFMA16(afl[m], bfh[n], acc[m][n]);
                acc[m][n] = MFMA16(afh[m], bfl[n], acc[m][n]);
                acc[m][n] = MFMA16(afh[m], bfh[n], acc[m][n]);
            }
        __syncthreads();
    }

    int sec = n0 >> 10;  // tile-uniform: 0=q 1=k 2=v 3=g (128 | 1024)
#pragma unroll
    for (int m = 0; m < 4; ++m)
#pragma unroll
        for (int n = 0; n < 4; ++n)
#pragma unroll
            for (int j = 0; j < 4; ++j) {
                int gm = m0 + wm * 64 + m * 16 + kg * 4 + j;   // token row
                int gn = n0 + wn * 64 + n * 16 + r;            // feature col
                float x = acc[m][n][j];
                if constexpr (EPI == 1) {
                    outF[(size_t)gm * 1024 + gn] = x;
                } else {
                    float p = silu_f(x);
                    if (sec == 3) {
                        G[(size_t)gm * Dc + (gn & 1023)] = p;
                    } else {
                        int f = gn & 1023, hd = f >> 6, d = f & 63;
                        int bb = gm >> 11, s = gm & 2047;
                        __bf16 hi = (__bf16)p;
                        __bf16 lo = (__bf16)(p - (float)hi);
                        if (sec == 0) {
                            size_t idx = ((size_t)(bb * Hc + hd) * Sc + s) * HDc + d;
                            Qh[idx] = hi; Ql[idx] = lo;
                        } else if (sec == 1) {
                            size_t idx = ((size_t)(bb * Hc + hd) * Sc + s) * HDc + d;
                            Kh[idx] = hi; Kl[idx] = lo;
                        } else {  // v stored transposed: [b,h,d,s]
                            size_t idx = ((size_t)(bb * Hc + hd) * HDc + d) * Sc + s;
                            Vh[idx] = hi; Vl[idx] = lo;
                        }
                    }
                }
            }
}

// --------------------------- fused attention v6 ----------------------------
// grid 512 (XCD-swizzled): b(2) x h(16) x qb(16 tiles of 128 q-rows).
// 512 threads = 8 waves x 16 q-rows. Q/K hi+lo (3-term QK^T); P and V
// single bf16 (1-term PV). K hi/lo + V hi staged per block via the
// r7/r8-verified reg->ds_write->__syncthreads two-barrier protocol.
__global__ __launch_bounds__(512) void attn6_kernel(
    const __bf16* __restrict__ Qh, const __bf16* __restrict__ Ql,
    const __bf16* __restrict__ Kh, const __bf16* __restrict__ Kl,
    const __bf16* __restrict__ Vh,
    const float* __restrict__ G,
    const unsigned long long* __restrict__ mbits,
    const float* __restrict__ invn,
    const float* __restrict__ gamma, const float* __restrict__ beta,
    __bf16* __restrict__ Oh, __bf16* __restrict__ Ol)
{
    __shared__ __bf16 sKt[2][64 * 72];     // [hi/lo][key][d]   144B rows
    __shared__ __bf16 sVt[64 * 72];        // [d][key]          (hi only)
    __shared__ __bf16 sw[8][16 * 72];      // per-wave score tile (hi only)

    // bijective XCD swizzle: 512 = 8 XCDs x 64 consecutive blocks
    int blk = (blockIdx.x & 7) * 64 + (blockIdx.x >> 3);
    int b = blk >> 8, h = (blk >> 4) & 15, qb = blk & 15;
    int tid = threadIdx.x, lane = tid & 63, wid = tid >> 6;   // wid 0..7
    int r = lane & 15, kg = lane >> 4;
    int q0 = qb * 128 + wid * 16;
    size_t bh = (size_t)b * Hc + h;
    const __bf16* Qhp = Qh + bh * (Sc * HDc);
    const __bf16* Qlp = Ql + bh * (Sc * HDc);
    const __bf16* Khp = Kh + bh * (Sc * HDc);
    const __bf16* Klp = Kl + bh * (Sc * HDc);
    const __bf16* Vhp = Vh + bh * (HDc * Sc);

    // Q fragments held in registers across the whole k loop
    bf16x8 qfh[2], qfl[2];
#pragma unroll
    for (int t = 0; t < 2; ++t) {
        size_t qa = (size_t)(q0 + r) * HDc + t * 32 + kg * 8;
        qfh[t] = *(const bf16x8*)&Qhp[qa];
        qfl[t] = *(const bf16x8*)&Qlp[qa];
    }
    float invr[4];
    const unsigned long long* mrow[4];
#pragma unroll
    for (int j = 0; j < 4; ++j) {
        int q = q0 + kg * 4 + j;
        invr[j] = invn[b * Sc + q];
        mrow[j] = mbits + (size_t)(b * Sc + q) * (Sc / 64);
    }
    float gam[4], bet[4];
#pragma unroll
    for (int n = 0; n < 4; ++n) { gam[n] = gamma[n * 16 + r]; bet[n] = beta[n * 16 + r]; }

    f32x4 oacc[4] = {};
    __bf16* swh = &sw[wid][0];

    // ---- staging: 512 threads cover 64 rows x 64 cols, 8 elems each ----
    int sr  = tid >> 3;                 // 0..63
    int sc0 = (tid & 7) * 8;            // 0,8,..,56
    const __bf16* gKh = Khp + (size_t)sr * HDc + sc0;   // + k0*HDc
    const __bf16* gKl = Klp + (size_t)sr * HDc + sc0;
    const __bf16* gVh = Vhp + (size_t)sr * Sc + sc0;    // + k0

    bf16x8 rKh, rKl, rVh;
    auto LOADT = [&](int kt) {
        int k0 = kt * 64;
        rKh = *(const bf16x8*)&gKh[(size_t)k0 * HDc];
        rKl = *(const bf16x8*)&gKl[(size_t)k0 * HDc];
        rVh = *(const bf16x8*)&gVh[k0];
    };
    auto WRITET = [&]() {
        *(bf16x8*)&sKt[0][sr * 72 + sc0] = rKh;
        *(bf16x8*)&sKt[1][sr * 72 + sc0] = rKl;
        *(bf16x8*)&sVt[sr * 72 + sc0] = rVh;
    };

    LOADT(0);

    for (int kt = 0; kt < Sc / 64; ++kt) {
        if (kt) __syncthreads();    // all reads of previous tile retired
        WRITET();
        __syncthreads();            // tile visible to all waves
        if (kt < 31) LOADT(kt + 1); // prefetch next tile (regs only)

        // ---- QK^T (3-term split), K from LDS ----
        f32x4 sc[4];
#pragma unroll
        for (int n = 0; n < 4; ++n) {
            f32x4 s = {0.f, 0.f, 0.f, 0.f};
#pragma unroll
            for (int t = 0; t < 2; ++t) {
                int ka = (n * 16 + r) * 72 + t * 32 + kg * 8;
                bf16x8 kfh = *(const bf16x8*)&sKt[0][ka];
                bf16x8 kfl = *(const bf16x8*)&sKt[1][ka];
                s = MFMA16(qfl[t], kfh, s);
                s = MFMA16(qfh[t], kfl, s);
                s = MFMA16(qfh[t], kfh, s);
            }
            sc[n] = s;
        }
        // ---- score epilogue (P -> single bf16 in LDS) ----
        unsigned long long mw[4];
#pragma unroll
        for (int j = 0; j < 4; ++j) mw[j] = mrow[j][kt];
#pragma unroll
        for (int n = 0; n < 4; ++n)
#pragma unroll
            for (int j = 0; j < 4; ++j) {
                float x = sc[n][j] * SCALE_C;
                float w = ((mw[j] >> (n * 16 + r)) & 1ULL) ? silu_f(x) * invr[j] : 0.0f;
                swh[(kg * 4 + j) * 72 + n * 16 + r] = (__bf16)w;
            }
        // wave-local LDS round-trip
        // ---- PV (1-term): P bf16 x V bf16 ----
#pragma unroll
        for (int t2 = 0; t2 < 2; ++t2) {
            bf16x8 wfh = *(const bf16x8*)&swh[r * 72 + t2 * 32 + kg * 8];
#pragma unroll
            for (int n2 = 0; n2 < 4; ++n2) {
                int va = (n2 * 16 + r) * 72 + t2 * 32 + kg * 8;
                bf16x8 vfh = *(const bf16x8*)&sVt[va];
                oacc[n2] = MFMA16(wfh, vfh, oacc[n2]);
            }
        }
    }

    // ---- LayerNorm over hd=64 + gate ----
    float sum[4];
#pragma unroll
    for (int j = 0; j < 4; ++j)
        sum[j] = oacc[0][j] + oacc[1][j] + oacc[2][j] + oacc[3][j];
#pragma unroll
    for (int off = 1; off < 16; off <<= 1)
#pragma unroll
        for (int j = 0; j < 4; ++j) sum[j] += __shfl_xor(sum[j], off, 64);
    float mean[4], vs[4];
#pragma unroll
    for (int j = 0; j < 4; ++j) mean[j] = sum[j] * (1.0f / 64.0f);
#pragma unroll
    for (int j = 0; j < 4; ++j) {
        float a = 0.f;
#pragma unroll
        for (int n2 = 0; n2 < 4; ++n2) {
            float dlt = oacc[n2][j] - mean[j];
            a += dlt * dlt;
        }
        vs[j] = a;
    }
#pragma unroll
    for (int off = 1; off < 16; off <<= 1)
#pragma unroll
        for (int j = 0; j < 4; ++j) vs[j] += __shfl_xor(vs[j], off, 64);
    float rstd[4];
#pragma unroll
    for (int j = 0; j < 4; ++j) rstd[j] = rsqrtf(vs[j] * (1.0f / 64.0f) + LN_EPS_C);

#pragma unroll
    for (int n2 = 0; n2 < 4; ++n2)
#pragma unroll
        for (int j = 0; j < 4; ++j) {
            int q = q0 + kg * 4 + j;
            int d = n2 * 16 + r;
            float x = (oacc[n2][j] - mean[j]) * rstd[j] * gam[n2] + bet[n2];
            size_t o = (size_t)(b * Sc + q) * Dc + h * HDc + d;
            float res = x * G[o];
            __bf16 hi = (__bf16)res;
            __bf16 lo = (__bf16)(res - (float)hi);
            Oh[o] = hi; Ol[o] = lo;
        }
}

// ---------------------------------------------------------------------------
extern "C" void kernel_launch(void* const* d_in, const int* in_sizes, int n_in,
                              void* d_out, int out_size, void* d_ws, size_t ws_size,
                              hipStream_t stream)
{
    const float* tokens = (const float*)d_in[0];
    const int*   maskp  = (const int*)d_in[1];
    const float* Wqkuv  = (const float*)d_in[2];
    const float* Wout   = (const float*)d_in[3];
    const float* gamma  = (const float*)d_in[4];
    const float* beta   = (const float*)d_in[5];
    float* out = (float*)d_out;

    char* ws = (char*)d_ws;
    size_t off = 0;
    auto alloc = [&](size_t bytes) -> void* {
        void* p = ws + off;
        off = (off + bytes + 255) & ~(size_t)255;
        return p;
    };
    const size_t MK = (size_t)4096 * 1024;
    __bf16* Xhi  = (__bf16*)alloc(MK * 2);
    __bf16* Xlo  = (__bf16*)alloc(MK * 2);
    __bf16* Wqth = (__bf16*)alloc((size_t)4096 * 1024 * 2);
    __bf16* Wqtl = (__bf16*)alloc((size_t)4096 * 1024 * 2);
    __bf16* Woth = (__bf16*)alloc((size_t)1024 * 1024 * 2);
    __bf16* Wotl = (__bf16*)alloc((size_t)1024 * 1024 * 2);
    __bf16* Qhp  = (__bf16*)alloc(MK * 2);
    __bf16* Qlp  = (__bf16*)alloc(MK * 2);
    __bf16* Khp  = (__bf16*)alloc(MK * 2);
    __bf16* Klp  = (__bf16*)alloc(MK * 2);
    __bf16* Vhp  = (__bf16*)alloc(MK * 2);
    __bf16* Vlp  = (__bf16*)alloc(MK * 2);
    float*  Gp   = (float*)alloc(MK * 4);
    __bf16* Ohp  = (__bf16*)alloc(MK * 2);
    __bf16* Olp  = (__bf16*)alloc(MK * 2);
    float*  invn = (float*)alloc((size_t)4096 * 4);
    unsigned long long* mbits = (unsigned long long*)alloc((size_t)4096 * 32 * 8);

    convert_split_kernel<<<(int)(MK / 4 / 256), 256, 0, stream>>>(tokens, Xhi, Xlo, (int)(MK / 4));
    transpose_split_kernel<<<dim3(16, 64), 256, 0, stream>>>(Wqkuv, Wqth, Wqtl, 1024, 4096);
    transpose_split_kernel<<<dim3(16, 16), 256, 0, stream>>>(Wout,  Woth, Wotl, 1024, 1024);
    mask_prep_kernel<<<1024, 256, 0, stream>>>(maskp, mbits, invn);
    gemm_split_kernel<0><<<dim3(32, 32), 256, 0, stream>>>(
        Xhi, Xlo, Wqth, Wqtl, 1024, nullptr,
        Qhp, Qlp, Khp, Klp, Vhp, Vlp, Gp);
    attn6_kernel<<<512, 512, 0, stream>>>(
        Qhp, Qlp, Khp, Klp, Vhp, Gp, mbits, invn, gamma, beta, Ohp, Olp);
    gemm_split_kernel<1><<<dim3(32, 8), 256, 0, stream>>>(
        Ohp, Olp, Woth, Wotl, 1024, out,
        nullptr, nullptr, nullptr, nullptr, nullptr, nullptr, nullptr);
}

// Round 11
// 370.558 us; speedup vs baseline: 2.4246x; 1.1872x over previous
//
#include <hip/hip_runtime.h>
#include <math.h>

// ---------------------------------------------------------------------------
// HybridSiLUGatedAttention on MI355X (gfx950)
// B=2, S=2048, D=1024, H=16, hd=64.
// Round 11: GEMM term cuts (numerics-guided, structure identical to r10).
//  - gemm<0> (proj): A=tokens hi/lo, B=W single bf16 -> 2-term (was 3).
//  - gemm<1> (out):  A=attended single bf16, B=W single bf16 -> 1-term.
//  - W transpose emits hi only; attn epilogue emits Oh only; V lo dropped.
// Error budget: +~1e-3 (proj path) +~5e-3..1e-2 (out path) on top of r10's
// 0.0156, vs threshold 0.073. Attention kernel unchanged from r10 (passing).
// ---------------------------------------------------------------------------

typedef __bf16 bf16x8 __attribute__((ext_vector_type(8)));
typedef __bf16 bf16x4 __attribute__((ext_vector_type(4)));
typedef float  f32x4  __attribute__((ext_vector_type(4)));

#define MFMA16(A, B, C) __builtin_amdgcn_mfma_f32_16x16x32_bf16((A), (B), (C), 0, 0, 0)

constexpr int   Sc   = 2048;
constexpr int   Dc   = 1024;
constexpr int   Hc   = 16;
constexpr int   HDc  = 64;
constexpr float SCALE_C = 0.125f;   // 1/sqrt(64)
constexpr float LN_EPS_C = 1e-5f;

__device__ __forceinline__ float silu_f(float x) {
    return x / (1.0f + __expf(-x));
}

// --------------------------- elementwise fp32 -> hi/lo bf16 ----------------
__global__ __launch_bounds__(256) void convert_split_kernel(
    const float* __restrict__ X, __bf16* __restrict__ Hi, __bf16* __restrict__ Lo, int n4)
{
    int i = blockIdx.x * 256 + threadIdx.x;
    if (i >= n4) return;
    float4 v = ((const float4*)X)[i];
    float vv[4] = {v.x, v.y, v.z, v.w};
    bf16x4 h, l;
#pragma unroll
    for (int e = 0; e < 4; ++e) {
        __bf16 hh = (__bf16)vv[e];
        h[e] = hh;
        l[e] = (__bf16)(vv[e] - (float)hh);
    }
    ((bf16x4*)Hi)[i] = h;
    ((bf16x4*)Lo)[i] = l;
}

// ------------------- transpose W[K][N] -> T[N][K], single bf16 -------------
__global__ __launch_bounds__(256) void transpose_bf16_kernel(
    const float* __restrict__ W, __bf16* __restrict__ Thi, int K, int N)
{
    __shared__ float tile[64][65];
    int kb = blockIdx.x * 64, nb = blockIdx.y * 64;
    int t = threadIdx.x;
    int i  = t >> 2;            // 0..63
    int c0 = (t & 3) * 16;      // 0,16,32,48
    const float* src = W + (size_t)(kb + i) * N + nb + c0;
#pragma unroll
    for (int e = 0; e < 4; ++e) {
        float4 v = ((const float4*)src)[e];
        tile[i][c0 + e * 4 + 0] = v.x;
        tile[i][c0 + e * 4 + 1] = v.y;
        tile[i][c0 + e * 4 + 2] = v.z;
        tile[i][c0 + e * 4 + 3] = v.w;
    }
    __syncthreads();
    int j = i;  // n-offset
#pragma unroll
    for (int e = 0; e < 4; ++e) {
        bf16x4 h;
#pragma unroll
        for (int u = 0; u < 4; ++u)
            h[u] = (__bf16)tile[c0 + e * 4 + u][j];
        size_t o = (size_t)(nb + j) * K + kb + c0 + e * 4;
        *(bf16x4*)&Thi[o] = h;
    }
}

// -------- mask [B,1,S,S] -> row bit-pack [row][S/64] + invnorm -------------
__global__ __launch_bounds__(256) void mask_prep_kernel(
    const int* __restrict__ mask, unsigned long long* __restrict__ bits,
    float* __restrict__ invn)
{
    int lane = threadIdx.x & 63, wid = threadIdx.x >> 6;
    int row = blockIdx.x * 4 + wid;          // 0..4095  (= b*2048+q)
    const int* mr = mask + (size_t)row * Sc;
    int cnt = 0;
    for (int t = 0; t < Sc / 64; ++t) {
        int m = mr[t * 64 + lane];
        unsigned long long w = __ballot(m != 0);
        if (lane == 0) bits[(size_t)row * (Sc / 64) + t] = w;
        cnt += (int)__popcll(w);
    }
    if (lane == 0) invn[row] = rsqrtf(fmaxf((float)cnt, 1.0f));
}

// --------------------------- reduced-term GEMM -----------------------------
// C[M][N] = A[M][K] * B^T[N][K]   (both operands stored K-contiguous)
// EPI==0: A hi/lo (2-term), silu epilogue, scatter to Q/K hi-lo, V hi, G.
// EPI==1: A single bf16 (1-term), plain fp32 out (N=1024).
template<int EPI>
__global__ __launch_bounds__(256) void gemm2_kernel(
    const __bf16* __restrict__ Ah, const __bf16* __restrict__ Al,
    const __bf16* __restrict__ Bh, int Kdim,
    float* __restrict__ outF,
    __bf16* __restrict__ Qh, __bf16* __restrict__ Ql,
    __bf16* __restrict__ Kh, __bf16* __restrict__ Kl,
    __bf16* __restrict__ Vh, float* __restrict__ G)
{
    constexpr int LSTR = 40;               // padded LDS row (bf16)
    constexpr int NA = (EPI == 0) ? 2 : 1;
    __shared__ __bf16 sA[NA][128 * LSTR];
    __shared__ __bf16 sB[128 * LSTR];
    int tid = threadIdx.x, lane = tid & 63, wid = tid >> 6;
    int r = lane & 15, kg = lane >> 4;
    int wm = wid >> 1, wn = wid & 1;
    int m0 = blockIdx.x * 128, n0 = blockIdx.y * 128;
    int c1r = tid >> 2;                    // 0..63
    int ck  = (tid & 3) * 8;               // 0,8,16,24
    int c2r = c1r + 64;

    f32x4 acc[4][4] = {};

    for (int kt = 0; kt < Kdim; kt += 32) {
        *(bf16x8*)&sA[0][c1r * LSTR + ck] = *(const bf16x8*)&Ah[(size_t)(m0 + c1r) * Kdim + kt + ck];
        *(bf16x8*)&sA[0][c2r * LSTR + ck] = *(const bf16x8*)&Ah[(size_t)(m0 + c2r) * Kdim + kt + ck];
        if constexpr (EPI == 0) {
            *(bf16x8*)&sA[1][c1r * LSTR + ck] = *(const bf16x8*)&Al[(size_t)(m0 + c1r) * Kdim + kt + ck];
            *(bf16x8*)&sA[1][c2r * LSTR + ck] = *(const bf16x8*)&Al[(size_t)(m0 + c2r) * Kdim + kt + ck];
        }
        *(bf16x8*)&sB[c1r * LSTR + ck] = *(const bf16x8*)&Bh[(size_t)(n0 + c1r) * Kdim + kt + ck];
        *(bf16x8*)&sB[c2r * LSTR + ck] = *(const bf16x8*)&Bh[(size_t)(n0 + c2r) * Kdim + kt + ck];
        __syncthreads();

        bf16x8 afh[4], afl[4], bfh[4];
#pragma unroll
        for (int m = 0; m < 4; ++m) {
            int row = wm * 64 + m * 16 + r;
            afh[m] = *(bf16x8*)&sA[0][row * LSTR + kg * 8];
            if constexpr (EPI == 0)
                afl[m] = *(bf16x8*)&sA[1][row * LSTR + kg * 8];
        }
#pragma unroll
        for (int n = 0; n < 4; ++n) {
            int col = wn * 64 + n * 16 + r;
            bfh[n] = *(bf16x8*)&sB[col * LSTR + kg * 8];
        }
#pragma unroll
        for (int m = 0; m < 4; ++m)
#pragma unroll
            for (int n = 0; n < 4; ++n) {
                if constexpr (EPI == 0)
                    acc[m][n] = MFMA16(afl[m], bfh[n], acc[m][n]);
                acc[m][n] = MFMA16(afh[m], bfh[n], acc[m][n]);
            }
        __syncthreads();
    }

    int sec = n0 >> 10;  // tile-uniform: 0=q 1=k 2=v 3=g (128 | 1024)
#pragma unroll
    for (int m = 0; m < 4; ++m)
#pragma unroll
        for (int n = 0; n < 4; ++n)
#pragma unroll
            for (int j = 0; j < 4; ++j) {
                int gm = m0 + wm * 64 + m * 16 + kg * 4 + j;   // token row
                int gn = n0 + wn * 64 + n * 16 + r;            // feature col
                float x = acc[m][n][j];
                if constexpr (EPI == 1) {
                    outF[(size_t)gm * 1024 + gn] = x;
                } else {
                    float p = silu_f(x);
                    if (sec == 3) {
                        G[(size_t)gm * Dc + (gn & 1023)] = p;
                    } else {
                        int f = gn & 1023, hd = f >> 6, d = f & 63;
                        int bb = gm >> 11, s = gm & 2047;
                        if (sec == 0) {
                            size_t idx = ((size_t)(bb * Hc + hd) * Sc + s) * HDc + d;
                            __bf16 hi = (__bf16)p;
                            Qh[idx] = hi; Ql[idx] = (__bf16)(p - (float)hi);
                        } else if (sec == 1) {
                            size_t idx = ((size_t)(bb * Hc + hd) * Sc + s) * HDc + d;
                            __bf16 hi = (__bf16)p;
                            Kh[idx] = hi; Kl[idx] = (__bf16)(p - (float)hi);
                        } else {  // v stored transposed: [b,h,d,s], hi only
                            size_t idx = ((size_t)(bb * Hc + hd) * HDc + d) * Sc + s;
                            Vh[idx] = (__bf16)p;
                        }
                    }
                }
            }
}

// --------------------------- fused attention v6 ----------------------------
// grid 512 (XCD-swizzled): b(2) x h(16) x qb(16 tiles of 128 q-rows).
// 512 threads = 8 waves x 16 q-rows. Q/K hi+lo (3-term QK^T); P and V
// single bf16 (1-term PV). K hi/lo + V hi staged per block via the
// r7/r8-verified reg->ds_write->__syncthreads two-barrier protocol.
// Output: Oh single bf16 (lo dropped — out-proj is 1-term now).
__global__ __launch_bounds__(512) void attn6_kernel(
    const __bf16* __restrict__ Qh, const __bf16* __restrict__ Ql,
    const __bf16* __restrict__ Kh, const __bf16* __restrict__ Kl,
    const __bf16* __restrict__ Vh,
    const float* __restrict__ G,
    const unsigned long long* __restrict__ mbits,
    const float* __restrict__ invn,
    const float* __restrict__ gamma, const float* __restrict__ beta,
    __bf16* __restrict__ Oh)
{
    __shared__ __bf16 sKt[2][64 * 72];     // [hi/lo][key][d]   144B rows
    __shared__ __bf16 sVt[64 * 72];        // [d][key]          (hi only)
    __shared__ __bf16 sw[8][16 * 72];      // per-wave score tile (hi only)

    // bijective XCD swizzle: 512 = 8 XCDs x 64 consecutive blocks
    int blk = (blockIdx.x & 7) * 64 + (blockIdx.x >> 3);
    int b = blk >> 8, h = (blk >> 4) & 15, qb = blk & 15;
    int tid = threadIdx.x, lane = tid & 63, wid = tid >> 6;   // wid 0..7
    int r = lane & 15, kg = lane >> 4;
    int q0 = qb * 128 + wid * 16;
    size_t bh = (size_t)b * Hc + h;
    const __bf16* Qhp = Qh + bh * (Sc * HDc);
    const __bf16* Qlp = Ql + bh * (Sc * HDc);
    const __bf16* Khp = Kh + bh * (Sc * HDc);
    const __bf16* Klp = Kl + bh * (Sc * HDc);
    const __bf16* Vhp = Vh + bh * (HDc * Sc);

    // Q fragments held in registers across the whole k loop
    bf16x8 qfh[2], qfl[2];
#pragma unroll
    for (int t = 0; t < 2; ++t) {
        size_t qa = (size_t)(q0 + r) * HDc + t * 32 + kg * 8;
        qfh[t] = *(const bf16x8*)&Qhp[qa];
        qfl[t] = *(const bf16x8*)&Qlp[qa];
    }
    float invr[4];
    const unsigned long long* mrow[4];
#pragma unroll
    for (int j = 0; j < 4; ++j) {
        int q = q0 + kg * 4 + j;
        invr[j] = invn[b * Sc + q];
        mrow[j] = mbits + (size_t)(b * Sc + q) * (Sc / 64);
    }
    float gam[4], bet[4];
#pragma unroll
    for (int n = 0; n < 4; ++n) { gam[n] = gamma[n * 16 + r]; bet[n] = beta[n * 16 + r]; }

    f32x4 oacc[4] = {};
    __bf16* swh = &sw[wid][0];

    // ---- staging: 512 threads cover 64 rows x 64 cols, 8 elems each ----
    int sr  = tid >> 3;                 // 0..63
    int sc0 = (tid & 7) * 8;            // 0,8,..,56
    const __bf16* gKh = Khp + (size_t)sr * HDc + sc0;   // + k0*HDc
    const __bf16* gKl = Klp + (size_t)sr * HDc + sc0;
    const __bf16* gVh = Vhp + (size_t)sr * Sc + sc0;    // + k0

    bf16x8 rKh, rKl, rVh;
    auto LOADT = [&](int kt) {
        int k0 = kt * 64;
        rKh = *(const bf16x8*)&gKh[(size_t)k0 * HDc];
        rKl = *(const bf16x8*)&gKl[(size_t)k0 * HDc];
        rVh = *(const bf16x8*)&gVh[k0];
    };
    auto WRITET = [&]() {
        *(bf16x8*)&sKt[0][sr * 72 + sc0] = rKh;
        *(bf16x8*)&sKt[1][sr * 72 + sc0] = rKl;
        *(bf16x8*)&sVt[sr * 72 + sc0] = rVh;
    };

    LOADT(0);

    for (int kt = 0; kt < Sc / 64; ++kt) {
        if (kt) __syncthreads();    // all reads of previous tile retired
        WRITET();
        __syncthreads();            // tile visible to all waves
        if (kt < 31) LOADT(kt + 1); // prefetch next tile (regs only)

        // ---- QK^T (3-term split), K from LDS ----
        f32x4 sc[4];
#pragma unroll
        for (int n = 0; n < 4; ++n) {
            f32x4 s = {0.f, 0.f, 0.f, 0.f};
#pragma unroll
            for (int t = 0; t < 2; ++t) {
                int ka = (n * 16 + r) * 72 + t * 32 + kg * 8;
                bf16x8 kfh = *(const bf16x8*)&sKt[0][ka];
                bf16x8 kfl = *(const bf16x8*)&sKt[1][ka];
                s = MFMA16(qfl[t], kfh, s);
                s = MFMA16(qfh[t], kfl, s);
                s = MFMA16(qfh[t], kfh, s);
            }
            sc[n] = s;
        }
        // ---- score epilogue (P -> single bf16 in LDS) ----
        unsigned long long mw[4];
#pragma unroll
        for (int j = 0; j < 4; ++j) mw[j] = mrow[j][kt];
#pragma unroll
        for (int n = 0; n < 4; ++n)
#pragma unroll
            for (int j = 0; j < 4; ++j) {
                float x = sc[n][j] * SCALE_C;
                float w = ((mw[j] >> (n * 16 + r)) & 1ULL) ? silu_f(x) * invr[j] : 0.0f;
                swh[(kg * 4 + j) * 72 + n * 16 + r] = (__bf16)w;
            }
        // wave-local LDS round-trip
        // ---- PV (1-term): P bf16 x V bf16 ----
#pragma unroll
        for (int t2 = 0; t2 < 2; ++t2) {
            bf16x8 wfh = *(const bf16x8*)&swh[r * 72 + t2 * 32 + kg * 8];
#pragma unroll
            for (int n2 = 0; n2 < 4; ++n2) {
                int va = (n2 * 16 + r) * 72 + t2 * 32 + kg * 8;
                bf16x8 vfh = *(const bf16x8*)&sVt[va];
                oacc[n2] = MFMA16(wfh, vfh, oacc[n2]);
            }
        }
    }

    // ---- LayerNorm over hd=64 + gate ----
    float sum[4];
#pragma unroll
    for (int j = 0; j < 4; ++j)
        sum[j] = oacc[0][j] + oacc[1][j] + oacc[2][j] + oacc[3][j];
#pragma unroll
    for (int off = 1; off < 16; off <<= 1)
#pragma unroll
        for (int j = 0; j < 4; ++j) sum[j] += __shfl_xor(sum[j], off, 64);
    float mean[4], vs[4];
#pragma unroll
    for (int j = 0; j < 4; ++j) mean[j] = sum[j] * (1.0f / 64.0f);
#pragma unroll
    for (int j = 0; j < 4; ++j) {
        float a = 0.f;
#pragma unroll
        for (int n2 = 0; n2 < 4; ++n2) {
            float dlt = oacc[n2][j] - mean[j];
            a += dlt * dlt;
        }
        vs[j] = a;
    }
#pragma unroll
    for (int off = 1; off < 16; off <<= 1)
#pragma unroll
        for (int j = 0; j < 4; ++j) vs[j] += __shfl_xor(vs[j], off, 64);
    float rstd[4];
#pragma unroll
    for (int j = 0; j < 4; ++j) rstd[j] = rsqrtf(vs[j] * (1.0f / 64.0f) + LN_EPS_C);

#pragma unroll
    for (int n2 = 0; n2 < 4; ++n2)
#pragma unroll
        for (int j = 0; j < 4; ++j) {
            int q = q0 + kg * 4 + j;
            int d = n2 * 16 + r;
            float x = (oacc[n2][j] - mean[j]) * rstd[j] * gam[n2] + bet[n2];
            size_t o = (size_t)(b * Sc + q) * Dc + h * HDc + d;
            Oh[o] = (__bf16)(x * G[o]);
        }
}

// ---------------------------------------------------------------------------
extern "C" void kernel_launch(void* const* d_in, const int* in_sizes, int n_in,
                              void* d_out, int out_size, void* d_ws, size_t ws_size,
                              hipStream_t stream)
{
    const float* tokens = (const float*)d_in[0];
    const int*   maskp  = (const int*)d_in[1];
    const float* Wqkuv  = (const float*)d_in[2];
    const float* Wout   = (const float*)d_in[3];
    const float* gamma  = (const float*)d_in[4];
    const float* beta   = (const float*)d_in[5];
    float* out = (float*)d_out;

    char* ws = (char*)d_ws;
    size_t off = 0;
    auto alloc = [&](size_t bytes) -> void* {
        void* p = ws + off;
        off = (off + bytes + 255) & ~(size_t)255;
        return p;
    };
    const size_t MK = (size_t)4096 * 1024;
    __bf16* Xhi  = (__bf16*)alloc(MK * 2);
    __bf16* Xlo  = (__bf16*)alloc(MK * 2);
    __bf16* Wqth = (__bf16*)alloc((size_t)4096 * 1024 * 2);
    __bf16* Woth = (__bf16*)alloc((size_t)1024 * 1024 * 2);
    __bf16* Qhp  = (__bf16*)alloc(MK * 2);
    __bf16* Qlp  = (__bf16*)alloc(MK * 2);
    __bf16* Khp  = (__bf16*)alloc(MK * 2);
    __bf16* Klp  = (__bf16*)alloc(MK * 2);
    __bf16* Vhp  = (__bf16*)alloc(MK * 2);
    float*  Gp   = (float*)alloc(MK * 4);
    __bf16* Ohp  = (__bf16*)alloc(MK * 2);
    float*  invn = (float*)alloc((size_t)4096 * 4);
    unsigned long long* mbits = (unsigned long long*)alloc((size_t)4096 * 32 * 8);

    convert_split_kernel<<<(int)(MK / 4 / 256), 256, 0, stream>>>(tokens, Xhi, Xlo, (int)(MK / 4));
    transpose_bf16_kernel<<<dim3(16, 64), 256, 0, stream>>>(Wqkuv, Wqth, 1024, 4096);
    transpose_bf16_kernel<<<dim3(16, 16), 256, 0, stream>>>(Wout,  Woth, 1024, 1024);
    mask_prep_kernel<<<1024, 256, 0, stream>>>(maskp, mbits, invn);
    gemm2_kernel<0><<<dim3(32, 32), 256, 0, stream>>>(
        Xhi, Xlo, Wqth, 1024, nullptr,
        Qhp, Qlp, Khp, Klp, Vhp, Gp);
    attn6_kernel<<<512, 512, 0, stream>>>(
        Qhp, Qlp, Khp, Klp, Vhp, Gp, mbits, invn, gamma, beta, Ohp);
    gemm2_kernel<1><<<dim3(32, 8), 256, 0, stream>>>(
        Ohp, nullptr, Woth, 1024, out,
        nullptr, nullptr, nullptr, nullptr, nullptr, nullptr);
}